// Round 17
// baseline (765.900 us; speedup 1.0000x reference)
//
#include <hip/hip_runtime.h>
#include <hip/hip_bf16.h>
#include <math.h>

// ============================================================================
// XCA transposed attention, bf16-MFMA, round 16:
//  - gemm_mfma: persistent-A multi-N blocks. Each block = (64-row m-tile,
//    batch, 4 consecutive 256-col n-tiles). A staged to LDS once (6 slabs);
//    B double-buffered, prefetch streams across all 24 (ng,kit) iterations;
//    r13 inner loop (1 __syncthreads/iter, XOR swizzle, gload_lds) verbatim.
//  - attn_fused / dwconv / transposes / cvt = round-13 (687.7us best) verbatim.
// ============================================================================

#define HW 65536
#define IMW 256

typedef short bf16x8 __attribute__((ext_vector_type(8)));
typedef float f32x4  __attribute__((ext_vector_type(4)));

__device__ __forceinline__ float bf2f(ushort u) {
    return __uint_as_float((uint)u << 16);
}
__device__ __forceinline__ ushort f2bf(float f) {
    uint i = __float_as_uint(f);
    return (ushort)((i + 0x7FFFu + ((i >> 16) & 1u)) >> 16);
}

__device__ __forceinline__ void gload16(const ushort* g, ushort* l) {
    __builtin_amdgcn_global_load_lds(
        (const __attribute__((address_space(1))) void*)g,
        (__attribute__((address_space(3))) void*)l,
        16, 0, 0);
}

// ---- flat fp32 -> bf16 (weights)
__global__ __launch_bounds__(256) void cvt_f32_bf16(const float* __restrict__ s,
                                                    ushort* __restrict__ d, int n)
{
    int i = blockIdx.x * 256 + threadIdx.x;
    if (i < n) d[i] = f2bf(s[i]);
}

// ---- fp32 [R][C] -> bf16 [C][R] transpose+convert, 64x64 tiles, z-sliced
__global__ __launch_bounds__(256) void cvt_transpose_f32(const float* __restrict__ src,
                                                         ushort* __restrict__ dst,
                                                         int R, int C,
                                                         long ssS, long ssD)
{
    __shared__ ushort Ls[64][72];
    int t = threadIdx.x;
    long z = blockIdx.z;
    src += z * ssS; dst += z * ssD;
    int c0 = blockIdx.x * 64, r0 = blockIdx.y * 64;
    {
        int r = t >> 2, cs = t & 3;
        const float* gp = src + (size_t)(r0 + r) * C + c0 + cs * 16;
        ushort tmp[16];
        #pragma unroll
        for (int q = 0; q < 4; ++q) {
            float4 v = *(const float4*)(gp + q * 4);
            tmp[q*4+0] = f2bf(v.x); tmp[q*4+1] = f2bf(v.y);
            tmp[q*4+2] = f2bf(v.z); tmp[q*4+3] = f2bf(v.w);
        }
        *(uint4*)&Ls[r][cs * 16]     = *(uint4*)&tmp[0];
        *(uint4*)&Ls[r][cs * 16 + 8] = *(uint4*)&tmp[8];
    }
    __syncthreads();
    {
        int cc = t & 63, seg = t >> 6;
        ushort tmp[16];
        #pragma unroll
        for (int j = 0; j < 16; ++j) tmp[j] = Ls[seg * 16 + j][cc];
        ushort* op = dst + (size_t)(c0 + cc) * R + r0 + seg * 16;
        *(uint4*)(op)     = *(uint4*)&tmp[0];
        *(uint4*)(op + 8) = *(uint4*)&tmp[8];
    }
}

// ---- bf16 [R][C] -> bf16 [C][R] transpose, 64x64 tiles, z-sliced
__global__ __launch_bounds__(256) void transpose_bf16(const ushort* __restrict__ src,
                                                      ushort* __restrict__ dst,
                                                      int R, int C,
                                                      long ssS, long ssD)
{
    __shared__ ushort Ls[64][72];
    int t = threadIdx.x;
    long z = blockIdx.z;
    src += z * ssS; dst += z * ssD;
    int c0 = blockIdx.x * 64, r0 = blockIdx.y * 64;
    {
        int r = t >> 2, cs = t & 3;
        const ushort* gp = src + (size_t)(r0 + r) * C + c0 + cs * 16;
        *(uint4*)&Ls[r][cs * 16]     = *(const uint4*)(gp);
        *(uint4*)&Ls[r][cs * 16 + 8] = *(const uint4*)(gp + 8);
    }
    __syncthreads();
    {
        int cc = t & 63, seg = t >> 6;
        ushort tmp[16];
        #pragma unroll
        for (int j = 0; j < 16; ++j) tmp[j] = Ls[seg * 16 + j][cc];
        ushort* op = dst + (size_t)(c0 + cc) * R + r0 + seg * 16;
        *(uint4*)(op)     = *(uint4*)&tmp[0];
        *(uint4*)(op + 8) = *(uint4*)&tmp[8];
    }
}

// ---- V [b][384+r][256][256] -> Vt [s=b*192+r][256][256]^T
__global__ __launch_bounds__(256) void transpose_v(const ushort* __restrict__ post,
                                                   ushort* __restrict__ vt)
{
    __shared__ ushort Ls[64][72];
    int t = threadIdx.x;
    int s = blockIdx.z;
    int b = s / 192, r = s - b * 192;
    const ushort* src = post + ((size_t)b * 576 + 384 + r) * HW;
    ushort*       dst = vt + (size_t)s * HW;
    int c0 = blockIdx.x * 64, r0 = blockIdx.y * 64;
    {
        int rr = t >> 2, cs = t & 3;
        const ushort* gp = src + (size_t)(r0 + rr) * IMW + c0 + cs * 16;
        *(uint4*)&Ls[rr][cs * 16]     = *(const uint4*)(gp);
        *(uint4*)&Ls[rr][cs * 16 + 8] = *(const uint4*)(gp + 8);
    }
    __syncthreads();
    {
        int cc = t & 63, seg = t >> 6;
        ushort tmp[16];
        #pragma unroll
        for (int j = 0; j < 16; ++j) tmp[j] = Ls[seg * 16 + j][cc];
        ushort* op = dst + (size_t)(c0 + cc) * IMW + r0 + seg * 16;
        *(uint4*)(op)     = *(uint4*)&tmp[0];
        *(uint4*)(op + 8) = *(uint4*)&tmp[8];
    }
}

// ---- MFMA GEMM, persistent-A: D[m][n] = sum_k A[m][k]*B[n][k] (+bias[m]).
// K=192 fixed. Block = (64-row m-tile, batch, 4 n-tiles of 256). A staged to
// LDS once (6 slabs of 32k); B dbuf streams over 24 (ng,kit) iterations.
// 1D grid, XCD-gather swizzle: NM m-blocks sharing B -> same XCD.
__global__ __launch_bounds__(256) void gemm_mfma(const ushort* __restrict__ A, int lda, long sliceA,
                                                 const ushort* __restrict__ B, int ldb, long sliceB,
                                                 void* __restrict__ Dp, int ldd, long sliceD,
                                                 const float* __restrict__ bias,
                                                 int outF32, int NM, int NGRP)
{
    // decode: r=lin&7, k=lin>>3, m=k%NM, g=(k/NM)*8+r, ngrp=g%NGRP, z=g/NGRP
    int lin = blockIdx.x;
    int r8 = lin & 7, k_ = lin >> 3;
    int m = k_ % NM, fg = k_ / NM;
    int g = fg * 8 + r8;
    int ngrp = g % NGRP;
    long z = g / NGRP;
    int m0 = m * 64;
    int nbase = ngrp * 1024;              // 4 n-tiles x 256 cols

    __shared__ ushort As[6][64][32];      // persistent A slabs (24 KB)
    __shared__ ushort Bs[2][256][32];     // B dbuf (32 KB)
    int t = threadIdx.x, wv = t >> 6, lane = t & 63;
    int fr = lane & 15, sg = lane >> 4;
    A += z * sliceA; B += z * sliceB;

    int rl   = wv * 16 + (lane >> 2);               // staging row in 64-group
    int chnk = (lane & 3) ^ ((lane >> 3) & 3);      // swizzled k-chunk (write side)
    const ushort* srcA = A + (size_t)(m0 + rl) * lda + chnk * 8;
    const ushort* srcB = B + (size_t)(nbase + rl) * ldb + chnk * 8;

    int sp = sg ^ ((fr >> 1) & 3);                  // read-side slot swizzle

    f32x4 acc[4][4];
    #pragma unroll
    for (int i = 0; i < 4; ++i)
        #pragma unroll
        for (int j = 0; j < 4; ++j) acc[i][j] = (f32x4){0.f, 0.f, 0.f, 0.f};

    // prologue: all 6 A slabs + B slab for (ng=0,kit=0)
    #pragma unroll
    for (int p = 0; p < 6; ++p)
        gload16(srcA + p * 32, &As[p][wv * 16][0]);
    #pragma unroll
    for (int q = 0; q < 4; ++q)
        gload16(srcB + (size_t)(q * 64) * ldb, &Bs[0][q * 64 + wv * 16][0]);
    __syncthreads();

    for (int it = 0; it < 24; ++it) {
        int kit = it % 6;
        int cur = it & 1;
        if (it + 1 < 24) {      // prefetch next B slab into other buffer
            int ng1 = (it + 1) / 6;
            int kc1 = ((it + 1) % 6) * 32;
            #pragma unroll
            for (int q = 0; q < 4; ++q)
                gload16(srcB + (size_t)(ng1 * 256 + q * 64) * ldb + kc1,
                        &Bs[cur ^ 1][q * 64 + wv * 16][0]);
        }
        bf16x8 a[4];
        #pragma unroll
        for (int i = 0; i < 4; ++i)
            a[i] = *(const bf16x8*)&As[kit][i * 16 + fr][sp * 8];
        #pragma unroll
        for (int j = 0; j < 4; ++j) {
            bf16x8 b = *(const bf16x8*)&Bs[cur][wv * 64 + j * 16 + fr][sp * 8];
            #pragma unroll
            for (int i = 0; i < 4; ++i)
                acc[i][j] = __builtin_amdgcn_mfma_f32_16x16x32_bf16(a[i], b, acc[i][j], 0, 0, 0);
        }
        __syncthreads();        // drains prefetch; protects Bs[cur] overwrite

        if (kit == 5) {         // epilogue for n-group it/6, then reset acc
            int nw0 = nbase + (it / 6) * 256 + wv * 64;
            int rbase = sg * 4;
            if (outF32) {
                float* D = (float*)Dp + z * sliceD;
                #pragma unroll
                for (int i = 0; i < 4; ++i) {
                    #pragma unroll
                    for (int r_ = 0; r_ < 4; ++r_) {
                        int mrow = m0 + i * 16 + rbase + r_;
                        float bv = bias ? bias[mrow] : 0.f;
                        #pragma unroll
                        for (int j = 0; j < 4; ++j)
                            D[(size_t)mrow * ldd + nw0 + j * 16 + fr] = acc[i][j][r_] + bv;
                    }
                }
            } else {
                ushort* D = (ushort*)Dp + z * sliceD;
                #pragma unroll
                for (int i = 0; i < 4; ++i) {
                    #pragma unroll
                    for (int r_ = 0; r_ < 4; ++r_) {
                        int mrow = m0 + i * 16 + rbase + r_;
                        float bv = bias ? bias[mrow] : 0.f;
                        #pragma unroll
                        for (int j = 0; j < 4; ++j)
                            D[(size_t)mrow * ldd + nw0 + j * 16 + fr] = f2bf(acc[i][j][r_] + bv);
                    }
                }
            }
            #pragma unroll
            for (int i = 0; i < 4; ++i)
                #pragma unroll
                for (int j = 0; j < 4; ++j) acc[i][j] = (f32x4){0.f, 0.f, 0.f, 0.f};
        }
    }
}

// ---- fused attention: per (m-tile 64, slice s): S=QK^T*t, softmax, O=P@Vt
// 1D grid, XCD-gather swizzle. Q/K/Vt staged via global_load_lds + swizzle.
__global__ __launch_bounds__(256) void attn_fused(const ushort* __restrict__ post,
                                                  const ushort* __restrict__ vt,
                                                  const float* __restrict__ temp,
                                                  ushort* __restrict__ O)
{
    __shared__ ushort Ws[64][32];     // Q tile
    __shared__ ushort Xs[256][32];    // K then Vt tile
    __shared__ ushort Ps[64][264];    // P (bf16)
    int t = threadIdx.x, wv = t >> 6, lane = t & 63;
    int fr = lane & 15, sg = lane >> 4;
    int lin = blockIdx.x;
    int r8 = lin & 7, k_ = lin >> 3;
    int mtile = k_ & 3, fg = k_ >> 2;
    int s = fg * 8 + r8;
    int b = s / 192, ch = s - b * 192;
    const ushort* Aq = post + ((size_t)b * 576 + ch) * HW;
    const ushort* Bk = Aq + (size_t)192 * HW;
    const ushort* Vt = vt + (size_t)s * HW;
    int m0 = mtile * 64;

    int rl   = wv * 16 + (lane >> 2);
    int chnk = (lane & 3) ^ ((lane >> 3) & 3);
    int sp   = sg ^ ((fr >> 1) & 3);
    const ushort* srcQ  = Aq + (size_t)(m0 + rl) * IMW + chnk * 8;
    const ushort* srcK0 = Bk + (size_t)(      rl) * IMW + chnk * 8;
    const ushort* srcK1 = Bk + (size_t)( 64 + rl) * IMW + chnk * 8;
    const ushort* srcK2 = Bk + (size_t)(128 + rl) * IMW + chnk * 8;
    const ushort* srcK3 = Bk + (size_t)(192 + rl) * IMW + chnk * 8;
    const ushort* srcV0 = Vt + (size_t)(      rl) * IMW + chnk * 8;
    const ushort* srcV1 = Vt + (size_t)( 64 + rl) * IMW + chnk * 8;
    const ushort* srcV2 = Vt + (size_t)(128 + rl) * IMW + chnk * 8;
    const ushort* srcV3 = Vt + (size_t)(192 + rl) * IMW + chnk * 8;

    f32x4 acc[16];
    #pragma unroll
    for (int i = 0; i < 16; ++i) acc[i] = (f32x4){0.f, 0.f, 0.f, 0.f};

    for (int k0 = 0; k0 < 256; k0 += 32) {
        gload16(srcQ  + k0, &Ws[wv * 16][0]);
        gload16(srcK0 + k0, &Xs[      wv * 16][0]);
        gload16(srcK1 + k0, &Xs[ 64 + wv * 16][0]);
        gload16(srcK2 + k0, &Xs[128 + wv * 16][0]);
        gload16(srcK3 + k0, &Xs[192 + wv * 16][0]);
        __syncthreads();
        bf16x8 a = *(const bf16x8*)&Ws[wv * 16 + fr][sp * 8];
        #pragma unroll
        for (int nt = 0; nt < 16; ++nt) {
            bf16x8 bfrag = *(const bf16x8*)&Xs[nt * 16 + fr][sp * 8];
            acc[nt] = __builtin_amdgcn_mfma_f32_16x16x32_bf16(a, bfrag, acc[nt], 0, 0, 0);
        }
        __syncthreads();
    }

    float tv = temp[ch >> 5];
    #pragma unroll
    for (int r_ = 0; r_ < 4; ++r_) {
        float v[16];
        float mx = -3.4e38f;
        #pragma unroll
        for (int nt = 0; nt < 16; ++nt) { v[nt] = acc[nt][r_] * tv; mx = fmaxf(mx, v[nt]); }
        #pragma unroll
        for (int sh = 1; sh < 16; sh <<= 1) mx = fmaxf(mx, __shfl_xor(mx, sh, 64));
        float sum = 0.f;
        #pragma unroll
        for (int nt = 0; nt < 16; ++nt) { v[nt] = __expf(v[nt] - mx); sum += v[nt]; }
        #pragma unroll
        for (int sh = 1; sh < 16; sh <<= 1) sum += __shfl_xor(sum, sh, 64);
        float inv = 1.f / sum;
        int ml = wv * 16 + sg * 4 + r_;
        #pragma unroll
        for (int nt = 0; nt < 16; ++nt)
            Ps[ml][fr + nt * 16] = f2bf(v[nt] * inv);
    }

    f32x4 acc2[16];
    #pragma unroll
    for (int i = 0; i < 16; ++i) acc2[i] = (f32x4){0.f, 0.f, 0.f, 0.f};

    for (int y0 = 0; y0 < 256; y0 += 32) {
        gload16(srcV0 + y0, &Xs[      wv * 16][0]);
        gload16(srcV1 + y0, &Xs[ 64 + wv * 16][0]);
        gload16(srcV2 + y0, &Xs[128 + wv * 16][0]);
        gload16(srcV3 + y0, &Xs[192 + wv * 16][0]);
        __syncthreads();
        bf16x8 a = *(const bf16x8*)&Ps[wv * 16 + fr][y0 + sg * 8];
        #pragma unroll
        for (int nt = 0; nt < 16; ++nt) {
            bf16x8 bfrag = *(const bf16x8*)&Xs[nt * 16 + fr][sp * 8];
            acc2[nt] = __builtin_amdgcn_mfma_f32_16x16x32_bf16(a, bfrag, acc2[nt], 0, 0, 0);
        }
        __syncthreads();
    }

    ushort* Op = O + (size_t)s * HW;
    int mrow = m0 + wv * 16 + sg * 4;
    #pragma unroll
    for (int r_ = 0; r_ < 4; ++r_) {
        #pragma unroll
        for (int nt = 0; nt < 16; ++nt)
            Op[(size_t)(mrow + r_) * IMW + fr + nt * 16] = f2bf(acc2[nt][r_]);
    }
}

// ---- depthwise 3x3 SAME + fused L2 row-norm, register-staged, shuffle halo
__global__ __launch_bounds__(256) void dw3x3_l2norm(const ushort* __restrict__ in,
                                                    const float* __restrict__ w,
                                                    const float* __restrict__ bias,
                                                    ushort* __restrict__ out)
{
    int t = threadIdx.x;
    int lane = t & 63, wv = t >> 6;
    int ch = blockIdx.y;
    int r0 = blockIdx.x * 16 + wv * 4;
    const ushort* img  = in  + ((size_t)blockIdx.z * 576 + ch) * HW;
    ushort*       outp = out + ((size_t)blockIdx.z * 576 + ch) * HW;
    int px = lane * 4;

    float rv[6][4], lv[6], rx[6];
    #pragma unroll
    for (int i = 0; i < 6; ++i) {
        int rr = r0 - 1 + i;
        if ((unsigned)rr <= 255u) {
            ushort4 cv = *(const ushort4*)&img[(size_t)rr * IMW + px];
            rv[i][0] = bf2f(cv.x); rv[i][1] = bf2f(cv.y);
            rv[i][2] = bf2f(cv.z); rv[i][3] = bf2f(cv.w);
        } else {
            rv[i][0] = rv[i][1] = rv[i][2] = rv[i][3] = 0.f;
        }
        float l = __shfl_up(rv[i][3], 1, 64);
        lv[i] = (lane == 0) ? 0.f : l;
        float r = __shfl_down(rv[i][0], 1, 64);
        rx[i] = (lane == 63) ? 0.f : r;
    }

    const float* wch = w + ch * 9;
    float bv = bias[ch];
    bool do_norm = (ch < 384);

    #pragma unroll
    for (int j = 0; j < 4; ++j) {
        float a0 = bv, a1 = bv, a2 = bv, a3 = bv;
        #pragma unroll
        for (int dy = 0; dy < 3; ++dy) {
            int i = j + dy;
            float w0 = wch[dy * 3], w1 = wch[dy * 3 + 1], w2 = wch[dy * 3 + 2];
            a0 += lv[i]    * w0 + rv[i][0] * w1 + rv[i][1] * w2;
            a1 += rv[i][0] * w0 + rv[i][1] * w1 + rv[i][2] * w2;
            a2 += rv[i][1] * w0 + rv[i][2] * w1 + rv[i][3] * w2;
            a3 += rv[i][2] * w0 + rv[i][3] * w1 + rx[i]    * w2;
        }
        if (do_norm) {
            float ss = a0 * a0 + a1 * a1 + a2 * a2 + a3 * a3;
            #pragma unroll
            for (int m = 1; m < 64; m <<= 1) ss += __shfl_xor(ss, m, 64);
            float inv = 1.0f / fmaxf(sqrtf(ss), 1e-12f);
            a0 *= inv; a1 *= inv; a2 *= inv; a3 *= inv;
        }
        ushort4 o;
        o.x = f2bf(a0); o.y = f2bf(a1); o.z = f2bf(a2); o.w = f2bf(a3);
        *(ushort4*)&outp[(size_t)(r0 + j) * IMW + px] = o;
    }
}

extern "C" void kernel_launch(void* const* d_in, const int* in_sizes, int n_in,
                              void* d_out, int out_size, void* d_ws, size_t ws_size,
                              hipStream_t stream)
{
    const float* x      = (const float*)d_in[0];
    const float* qkv_w  = (const float*)d_in[1];
    const float* qkv_b  = (const float*)d_in[2];
    const float* dw_w   = (const float*)d_in[3];
    const float* dw_b   = (const float*)d_in[4];
    const float* proj_w = (const float*)d_in[5];
    const float* proj_b = (const float*)d_in[6];
    const float* temp   = (const float*)d_in[7];
    float* out = (float*)d_out;

    const size_t off_wq   = 0;
    const size_t off_wp   = 110592;
    const size_t off_pre  = 262144;
    const size_t off_post = off_pre + (size_t)4 * 576 * HW;
    const size_t off_xt   = off_post + (size_t)4 * 576 * HW;
    const size_t total_us = off_xt + (size_t)4 * 192 * HW;
    if (ws_size < total_us * sizeof(ushort)) return;

    ushort* wsb  = (ushort*)d_ws;
    ushort* wq   = wsb + off_wq;
    ushort* wp   = wsb + off_wp;
    ushort* pre  = wsb + off_pre;
    ushort* post = wsb + off_post;
    ushort* xt   = wsb + off_xt;
    ushort* Obuf = pre;
    ushort* Otb  = pre + (size_t)4 * 192 * HW;

    const long SL = (long)192 * HW;

    cvt_f32_bf16<<<dim3(432), 256, 0, stream>>>(qkv_w, wq, 110592);
    cvt_f32_bf16<<<dim3(144), 256, 0, stream>>>(proj_w, wp, 36864);

    cvt_transpose_f32<<<dim3(1024, 3, 4), 256, 0, stream>>>(x, xt, 192, HW, SL, SL);
    // qkv: NM=9, NGRP=64 (4 n-tiles each), 4 batches -> 2304 blocks (288/9=32 ok)
    gemm_mfma<<<dim3(9 * 64 * 4), 256, 0, stream>>>(wq, 192, 0, xt, 192, SL,
                                                    pre, HW, (long)576 * HW,
                                                    qkv_b, 0, 9, 64);
    dw3x3_l2norm<<<dim3(16, 576, 4), 256, 0, stream>>>(pre, dw_w, dw_b, post);
    transpose_v<<<dim3(4, 4, 768), 256, 0, stream>>>(post, xt);
    attn_fused<<<dim3(4 * 768), 256, 0, stream>>>(post, xt, temp, Obuf);
    transpose_bf16<<<dim3(1024, 3, 4), 256, 0, stream>>>(Obuf, Otb, 192, HW, SL, SL);
    // proj: NM=3, NGRP=64, 4 batches -> 768 blocks (96/3=32 ok)
    gemm_mfma<<<dim3(3 * 64 * 4), 256, 0, stream>>>(wp, 192, 0, Otb, 192, SL,
                                                    out, HW, SL,
                                                    proj_b, 1, 3, 64);
}

// Round 18
// 725.891 us; speedup vs baseline: 1.0551x; 1.0551x over previous
//
#include <hip/hip_runtime.h>
#include <hip/hip_bf16.h>
#include <math.h>

// ============================================================================
// XCA transposed attention, bf16-MFMA, round 17:
//  - gemm_mfma: half-K burst loading. 2 mega-iterations of K=96; per half a
//    15-deep gload_lds burst (240B/lane in flight) -> one drain -> 48 MFMAs.
//    LDS 60KB (2 blocks/CU co-resident hide each other's bursts). XOR swizzle
//    and XCD-gather swizzle kept from r13.
//  - attn_fused / dwconv / transposes / cvt = round-13 (687.7us best) verbatim.
// ============================================================================

#define HW 65536
#define IMW 256

typedef short bf16x8 __attribute__((ext_vector_type(8)));
typedef float f32x4  __attribute__((ext_vector_type(4)));

__device__ __forceinline__ float bf2f(ushort u) {
    return __uint_as_float((uint)u << 16);
}
__device__ __forceinline__ ushort f2bf(float f) {
    uint i = __float_as_uint(f);
    return (ushort)((i + 0x7FFFu + ((i >> 16) & 1u)) >> 16);
}

__device__ __forceinline__ void gload16(const ushort* g, ushort* l) {
    __builtin_amdgcn_global_load_lds(
        (const __attribute__((address_space(1))) void*)g,
        (__attribute__((address_space(3))) void*)l,
        16, 0, 0);
}

// ---- flat fp32 -> bf16 (weights)
__global__ __launch_bounds__(256) void cvt_f32_bf16(const float* __restrict__ s,
                                                    ushort* __restrict__ d, int n)
{
    int i = blockIdx.x * 256 + threadIdx.x;
    if (i < n) d[i] = f2bf(s[i]);
}

// ---- fp32 [R][C] -> bf16 [C][R] transpose+convert, 64x64 tiles, z-sliced
__global__ __launch_bounds__(256) void cvt_transpose_f32(const float* __restrict__ src,
                                                         ushort* __restrict__ dst,
                                                         int R, int C,
                                                         long ssS, long ssD)
{
    __shared__ ushort Ls[64][72];
    int t = threadIdx.x;
    long z = blockIdx.z;
    src += z * ssS; dst += z * ssD;
    int c0 = blockIdx.x * 64, r0 = blockIdx.y * 64;
    {
        int r = t >> 2, cs = t & 3;
        const float* gp = src + (size_t)(r0 + r) * C + c0 + cs * 16;
        ushort tmp[16];
        #pragma unroll
        for (int q = 0; q < 4; ++q) {
            float4 v = *(const float4*)(gp + q * 4);
            tmp[q*4+0] = f2bf(v.x); tmp[q*4+1] = f2bf(v.y);
            tmp[q*4+2] = f2bf(v.z); tmp[q*4+3] = f2bf(v.w);
        }
        *(uint4*)&Ls[r][cs * 16]     = *(uint4*)&tmp[0];
        *(uint4*)&Ls[r][cs * 16 + 8] = *(uint4*)&tmp[8];
    }
    __syncthreads();
    {
        int cc = t & 63, seg = t >> 6;
        ushort tmp[16];
        #pragma unroll
        for (int j = 0; j < 16; ++j) tmp[j] = Ls[seg * 16 + j][cc];
        ushort* op = dst + (size_t)(c0 + cc) * R + r0 + seg * 16;
        *(uint4*)(op)     = *(uint4*)&tmp[0];
        *(uint4*)(op + 8) = *(uint4*)&tmp[8];
    }
}

// ---- bf16 [R][C] -> bf16 [C][R] transpose, 64x64 tiles, z-sliced
__global__ __launch_bounds__(256) void transpose_bf16(const ushort* __restrict__ src,
                                                      ushort* __restrict__ dst,
                                                      int R, int C,
                                                      long ssS, long ssD)
{
    __shared__ ushort Ls[64][72];
    int t = threadIdx.x;
    long z = blockIdx.z;
    src += z * ssS; dst += z * ssD;
    int c0 = blockIdx.x * 64, r0 = blockIdx.y * 64;
    {
        int r = t >> 2, cs = t & 3;
        const ushort* gp = src + (size_t)(r0 + r) * C + c0 + cs * 16;
        *(uint4*)&Ls[r][cs * 16]     = *(const uint4*)(gp);
        *(uint4*)&Ls[r][cs * 16 + 8] = *(const uint4*)(gp + 8);
    }
    __syncthreads();
    {
        int cc = t & 63, seg = t >> 6;
        ushort tmp[16];
        #pragma unroll
        for (int j = 0; j < 16; ++j) tmp[j] = Ls[seg * 16 + j][cc];
        ushort* op = dst + (size_t)(c0 + cc) * R + r0 + seg * 16;
        *(uint4*)(op)     = *(uint4*)&tmp[0];
        *(uint4*)(op + 8) = *(uint4*)&tmp[8];
    }
}

// ---- V [b][384+r][256][256] -> Vt [s=b*192+r][256][256]^T
__global__ __launch_bounds__(256) void transpose_v(const ushort* __restrict__ post,
                                                   ushort* __restrict__ vt)
{
    __shared__ ushort Ls[64][72];
    int t = threadIdx.x;
    int s = blockIdx.z;
    int b = s / 192, r = s - b * 192;
    const ushort* src = post + ((size_t)b * 576 + 384 + r) * HW;
    ushort*       dst = vt + (size_t)s * HW;
    int c0 = blockIdx.x * 64, r0 = blockIdx.y * 64;
    {
        int rr = t >> 2, cs = t & 3;
        const ushort* gp = src + (size_t)(r0 + rr) * IMW + c0 + cs * 16;
        *(uint4*)&Ls[rr][cs * 16]     = *(const uint4*)(gp);
        *(uint4*)&Ls[rr][cs * 16 + 8] = *(const uint4*)(gp + 8);
    }
    __syncthreads();
    {
        int cc = t & 63, seg = t >> 6;
        ushort tmp[16];
        #pragma unroll
        for (int j = 0; j < 16; ++j) tmp[j] = Ls[seg * 16 + j][cc];
        ushort* op = dst + (size_t)(c0 + cc) * IMW + r0 + seg * 16;
        *(uint4*)(op)     = *(uint4*)&tmp[0];
        *(uint4*)(op + 8) = *(uint4*)&tmp[8];
    }
}

// ---- MFMA GEMM: D[m][n] = sum_k A[m][k]*B[n][k] (+bias[m]), K=192 fixed.
// 1D grid, XCD-gather swizzle. Two K=96 halves; per half: 15-deep gload_lds
// burst -> drain -> 3x(16 MFMA). LDS 60KB single-buffer. Wave 64Mx64N.
__global__ __launch_bounds__(256) void gemm_mfma(const ushort* __restrict__ A, int lda, long sliceA,
                                                 const ushort* __restrict__ B, int ldb, long sliceB,
                                                 void* __restrict__ Dp, int ldd, long sliceD,
                                                 const float* __restrict__ bias,
                                                 int outF32, int NM, int NN)
{
    // decode: r=lin&7, k=lin>>3, m=k%NM, g=(k/NM)*8+r, n=g%NN, z=g/NN
    int lin = blockIdx.x;
    int r8 = lin & 7, kk_ = lin >> 3;
    int m = kk_ % NM, fg = kk_ / NM;
    int g = fg * 8 + r8;
    int nt_ = g % NN;
    long z = g / NN;
    int m0 = m * 64;
    int n0 = nt_ * 256;

    __shared__ ushort As[3][64][32];      // A slabs for one K=96 half (12 KB)
    __shared__ ushort Bs[3][256][32];     // B slabs for one K=96 half (48 KB)
    int t = threadIdx.x, wv = t >> 6, lane = t & 63;
    int fr = lane & 15, sg = lane >> 4;
    A += z * sliceA; B += z * sliceB;

    int rl   = wv * 16 + (lane >> 2);               // staging row in 64-group
    int chnk = (lane & 3) ^ ((lane >> 3) & 3);      // swizzled k-chunk (write side)
    const ushort* srcA = A + (size_t)(m0 + rl) * lda + chnk * 8;
    const ushort* srcB = B + (size_t)(n0 + rl) * ldb + chnk * 8;

    int sp = sg ^ ((fr >> 1) & 3);                  // read-side slot swizzle

    f32x4 acc[4][4];
    #pragma unroll
    for (int i = 0; i < 4; ++i)
        #pragma unroll
        for (int j = 0; j < 4; ++j) acc[i][j] = (f32x4){0.f, 0.f, 0.f, 0.f};

    #pragma unroll
    for (int half = 0; half < 2; ++half) {
        int kb = half * 96;
        // burst: 3 A slabs + 12 B slabs, all in flight together
        #pragma unroll
        for (int p = 0; p < 3; ++p)
            gload16(srcA + kb + p * 32, &As[p][wv * 16][0]);
        #pragma unroll
        for (int p = 0; p < 3; ++p)
            #pragma unroll
            for (int q = 0; q < 4; ++q)
                gload16(srcB + (size_t)(q * 64) * ldb + kb + p * 32,
                        &Bs[p][q * 64 + wv * 16][0]);
        __syncthreads();    // compiler emits vmcnt(0) drain here (intended)

        #pragma unroll
        for (int kit = 0; kit < 3; ++kit) {
            bf16x8 a[4];
            #pragma unroll
            for (int i = 0; i < 4; ++i)
                a[i] = *(const bf16x8*)&As[kit][i * 16 + fr][sp * 8];
            #pragma unroll
            for (int j = 0; j < 4; ++j) {
                bf16x8 b = *(const bf16x8*)&Bs[kit][wv * 64 + j * 16 + fr][sp * 8];
                #pragma unroll
                for (int i = 0; i < 4; ++i)
                    acc[i][j] = __builtin_amdgcn_mfma_f32_16x16x32_bf16(a[i], b, acc[i][j], 0, 0, 0);
            }
        }
        if (half == 0) __syncthreads();   // readers done before restage
    }

    int nw0 = n0 + wv * 64;
    int rbase = sg * 4;
    if (outF32) {
        float* D = (float*)Dp + z * sliceD;
        #pragma unroll
        for (int i = 0; i < 4; ++i) {
            #pragma unroll
            for (int r_ = 0; r_ < 4; ++r_) {
                int mrow = m0 + i * 16 + rbase + r_;
                float bv = bias ? bias[mrow] : 0.f;
                #pragma unroll
                for (int j = 0; j < 4; ++j)
                    D[(size_t)mrow * ldd + nw0 + j * 16 + fr] = acc[i][j][r_] + bv;
            }
        }
    } else {
        ushort* D = (ushort*)Dp + z * sliceD;
        #pragma unroll
        for (int i = 0; i < 4; ++i) {
            #pragma unroll
            for (int r_ = 0; r_ < 4; ++r_) {
                int mrow = m0 + i * 16 + rbase + r_;
                float bv = bias ? bias[mrow] : 0.f;
                #pragma unroll
                for (int j = 0; j < 4; ++j)
                    D[(size_t)mrow * ldd + nw0 + j * 16 + fr] = f2bf(acc[i][j][r_] + bv);
            }
        }
    }
}

// ---- fused attention: per (m-tile 64, slice s): S=QK^T*t, softmax, O=P@Vt
// 1D grid, XCD-gather swizzle. Q/K/Vt staged via global_load_lds + swizzle.
__global__ __launch_bounds__(256) void attn_fused(const ushort* __restrict__ post,
                                                  const ushort* __restrict__ vt,
                                                  const float* __restrict__ temp,
                                                  ushort* __restrict__ O)
{
    __shared__ ushort Ws[64][32];     // Q tile
    __shared__ ushort Xs[256][32];    // K then Vt tile
    __shared__ ushort Ps[64][264];    // P (bf16)
    int t = threadIdx.x, wv = t >> 6, lane = t & 63;
    int fr = lane & 15, sg = lane >> 4;
    int lin = blockIdx.x;
    int r8 = lin & 7, k_ = lin >> 3;
    int mtile = k_ & 3, fg = k_ >> 2;
    int s = fg * 8 + r8;
    int b = s / 192, ch = s - b * 192;
    const ushort* Aq = post + ((size_t)b * 576 + ch) * HW;
    const ushort* Bk = Aq + (size_t)192 * HW;
    const ushort* Vt = vt + (size_t)s * HW;
    int m0 = mtile * 64;

    int rl   = wv * 16 + (lane >> 2);
    int chnk = (lane & 3) ^ ((lane >> 3) & 3);
    int sp   = sg ^ ((fr >> 1) & 3);
    const ushort* srcQ  = Aq + (size_t)(m0 + rl) * IMW + chnk * 8;
    const ushort* srcK0 = Bk + (size_t)(      rl) * IMW + chnk * 8;
    const ushort* srcK1 = Bk + (size_t)( 64 + rl) * IMW + chnk * 8;
    const ushort* srcK2 = Bk + (size_t)(128 + rl) * IMW + chnk * 8;
    const ushort* srcK3 = Bk + (size_t)(192 + rl) * IMW + chnk * 8;
    const ushort* srcV0 = Vt + (size_t)(      rl) * IMW + chnk * 8;
    const ushort* srcV1 = Vt + (size_t)( 64 + rl) * IMW + chnk * 8;
    const ushort* srcV2 = Vt + (size_t)(128 + rl) * IMW + chnk * 8;
    const ushort* srcV3 = Vt + (size_t)(192 + rl) * IMW + chnk * 8;

    f32x4 acc[16];
    #pragma unroll
    for (int i = 0; i < 16; ++i) acc[i] = (f32x4){0.f, 0.f, 0.f, 0.f};

    for (int k0 = 0; k0 < 256; k0 += 32) {
        gload16(srcQ  + k0, &Ws[wv * 16][0]);
        gload16(srcK0 + k0, &Xs[      wv * 16][0]);
        gload16(srcK1 + k0, &Xs[ 64 + wv * 16][0]);
        gload16(srcK2 + k0, &Xs[128 + wv * 16][0]);
        gload16(srcK3 + k0, &Xs[192 + wv * 16][0]);
        __syncthreads();
        bf16x8 a = *(const bf16x8*)&Ws[wv * 16 + fr][sp * 8];
        #pragma unroll
        for (int nt = 0; nt < 16; ++nt) {
            bf16x8 bfrag = *(const bf16x8*)&Xs[nt * 16 + fr][sp * 8];
            acc[nt] = __builtin_amdgcn_mfma_f32_16x16x32_bf16(a, bfrag, acc[nt], 0, 0, 0);
        }
        __syncthreads();
    }

    float tv = temp[ch >> 5];
    #pragma unroll
    for (int r_ = 0; r_ < 4; ++r_) {
        float v[16];
        float mx = -3.4e38f;
        #pragma unroll
        for (int nt = 0; nt < 16; ++nt) { v[nt] = acc[nt][r_] * tv; mx = fmaxf(mx, v[nt]); }
        #pragma unroll
        for (int sh = 1; sh < 16; sh <<= 1) mx = fmaxf(mx, __shfl_xor(mx, sh, 64));
        float sum = 0.f;
        #pragma unroll
        for (int nt = 0; nt < 16; ++nt) { v[nt] = __expf(v[nt] - mx); sum += v[nt]; }
        #pragma unroll
        for (int sh = 1; sh < 16; sh <<= 1) sum += __shfl_xor(sum, sh, 64);
        float inv = 1.f / sum;
        int ml = wv * 16 + sg * 4 + r_;
        #pragma unroll
        for (int nt = 0; nt < 16; ++nt)
            Ps[ml][fr + nt * 16] = f2bf(v[nt] * inv);
    }

    f32x4 acc2[16];
    #pragma unroll
    for (int i = 0; i < 16; ++i) acc2[i] = (f32x4){0.f, 0.f, 0.f, 0.f};

    for (int y0 = 0; y0 < 256; y0 += 32) {
        gload16(srcV0 + y0, &Xs[      wv * 16][0]);
        gload16(srcV1 + y0, &Xs[ 64 + wv * 16][0]);
        gload16(srcV2 + y0, &Xs[128 + wv * 16][0]);
        gload16(srcV3 + y0, &Xs[192 + wv * 16][0]);
        __syncthreads();
        bf16x8 a = *(const bf16x8*)&Ps[wv * 16 + fr][y0 + sg * 8];
        #pragma unroll
        for (int nt = 0; nt < 16; ++nt) {
            bf16x8 bfrag = *(const bf16x8*)&Xs[nt * 16 + fr][sp * 8];
            acc2[nt] = __builtin_amdgcn_mfma_f32_16x16x32_bf16(a, bfrag, acc2[nt], 0, 0, 0);
        }
        __syncthreads();
    }

    ushort* Op = O + (size_t)s * HW;
    int mrow = m0 + wv * 16 + sg * 4;
    #pragma unroll
    for (int r_ = 0; r_ < 4; ++r_) {
        #pragma unroll
        for (int nt = 0; nt < 16; ++nt)
            Op[(size_t)(mrow + r_) * IMW + fr + nt * 16] = f2bf(acc2[nt][r_]);
    }
}

// ---- depthwise 3x3 SAME + fused L2 row-norm, register-staged, shuffle halo
__global__ __launch_bounds__(256) void dw3x3_l2norm(const ushort* __restrict__ in,
                                                    const float* __restrict__ w,
                                                    const float* __restrict__ bias,
                                                    ushort* __restrict__ out)
{
    int t = threadIdx.x;
    int lane = t & 63, wv = t >> 6;
    int ch = blockIdx.y;
    int r0 = blockIdx.x * 16 + wv * 4;
    const ushort* img  = in  + ((size_t)blockIdx.z * 576 + ch) * HW;
    ushort*       outp = out + ((size_t)blockIdx.z * 576 + ch) * HW;
    int px = lane * 4;

    float rv[6][4], lv[6], rx[6];
    #pragma unroll
    for (int i = 0; i < 6; ++i) {
        int rr = r0 - 1 + i;
        if ((unsigned)rr <= 255u) {
            ushort4 cv = *(const ushort4*)&img[(size_t)rr * IMW + px];
            rv[i][0] = bf2f(cv.x); rv[i][1] = bf2f(cv.y);
            rv[i][2] = bf2f(cv.z); rv[i][3] = bf2f(cv.w);
        } else {
            rv[i][0] = rv[i][1] = rv[i][2] = rv[i][3] = 0.f;
        }
        float l = __shfl_up(rv[i][3], 1, 64);
        lv[i] = (lane == 0) ? 0.f : l;
        float r = __shfl_down(rv[i][0], 1, 64);
        rx[i] = (lane == 63) ? 0.f : r;
    }

    const float* wch = w + ch * 9;
    float bv = bias[ch];
    bool do_norm = (ch < 384);

    #pragma unroll
    for (int j = 0; j < 4; ++j) {
        float a0 = bv, a1 = bv, a2 = bv, a3 = bv;
        #pragma unroll
        for (int dy = 0; dy < 3; ++dy) {
            int i = j + dy;
            float w0 = wch[dy * 3], w1 = wch[dy * 3 + 1], w2 = wch[dy * 3 + 2];
            a0 += lv[i]    * w0 + rv[i][0] * w1 + rv[i][1] * w2;
            a1 += rv[i][0] * w0 + rv[i][1] * w1 + rv[i][2] * w2;
            a2 += rv[i][1] * w0 + rv[i][2] * w1 + rv[i][3] * w2;
            a3 += rv[i][2] * w0 + rv[i][3] * w1 + rx[i]    * w2;
        }
        if (do_norm) {
            float ss = a0 * a0 + a1 * a1 + a2 * a2 + a3 * a3;
            #pragma unroll
            for (int m = 1; m < 64; m <<= 1) ss += __shfl_xor(ss, m, 64);
            float inv = 1.0f / fmaxf(sqrtf(ss), 1e-12f);
            a0 *= inv; a1 *= inv; a2 *= inv; a3 *= inv;
        }
        ushort4 o;
        o.x = f2bf(a0); o.y = f2bf(a1); o.z = f2bf(a2); o.w = f2bf(a3);
        *(ushort4*)&outp[(size_t)(r0 + j) * IMW + px] = o;
    }
}

extern "C" void kernel_launch(void* const* d_in, const int* in_sizes, int n_in,
                              void* d_out, int out_size, void* d_ws, size_t ws_size,
                              hipStream_t stream)
{
    const float* x      = (const float*)d_in[0];
    const float* qkv_w  = (const float*)d_in[1];
    const float* qkv_b  = (const float*)d_in[2];
    const float* dw_w   = (const float*)d_in[3];
    const float* dw_b   = (const float*)d_in[4];
    const float* proj_w = (const float*)d_in[5];
    const float* proj_b = (const float*)d_in[6];
    const float* temp   = (const float*)d_in[7];
    float* out = (float*)d_out;

    const size_t off_wq   = 0;
    const size_t off_wp   = 110592;
    const size_t off_pre  = 262144;
    const size_t off_post = off_pre + (size_t)4 * 576 * HW;
    const size_t off_xt   = off_post + (size_t)4 * 576 * HW;
    const size_t total_us = off_xt + (size_t)4 * 192 * HW;
    if (ws_size < total_us * sizeof(ushort)) return;

    ushort* wsb  = (ushort*)d_ws;
    ushort* wq   = wsb + off_wq;
    ushort* wp   = wsb + off_wp;
    ushort* pre  = wsb + off_pre;
    ushort* post = wsb + off_post;
    ushort* xt   = wsb + off_xt;
    ushort* Obuf = pre;
    ushort* Otb  = pre + (size_t)4 * 192 * HW;

    const long SL = (long)192 * HW;

    cvt_f32_bf16<<<dim3(432), 256, 0, stream>>>(qkv_w, wq, 110592);
    cvt_f32_bf16<<<dim3(144), 256, 0, stream>>>(proj_w, wp, 36864);

    cvt_transpose_f32<<<dim3(1024, 3, 4), 256, 0, stream>>>(x, xt, 192, HW, SL, SL);
    // qkv: NM=9, NN=256, 4 batches -> 9216 blocks
    gemm_mfma<<<dim3(9 * 256 * 4), 256, 0, stream>>>(wq, 192, 0, xt, 192, SL,
                                                     pre, HW, (long)576 * HW,
                                                     qkv_b, 0, 9, 256);
    dw3x3_l2norm<<<dim3(16, 576, 4), 256, 0, stream>>>(pre, dw_w, dw_b, post);
    transpose_v<<<dim3(4, 4, 768), 256, 0, stream>>>(post, xt);
    attn_fused<<<dim3(4 * 768), 256, 0, stream>>>(post, xt, temp, Obuf);
    transpose_bf16<<<dim3(1024, 3, 4), 256, 0, stream>>>(Obuf, Otb, 192, HW, SL, SL);
    // proj: NM=3, NN=256, 4 batches -> 3072 blocks
    gemm_mfma<<<dim3(3 * 256 * 4), 256, 0, stream>>>(wp, 192, 0, Otb, 192, SL,
                                                     out, HW, SL,
                                                     proj_b, 1, 3, 256);
}

// Round 19
// 718.533 us; speedup vs baseline: 1.0659x; 1.0102x over previous
//
#include <hip/hip_runtime.h>
#include <hip/hip_bf16.h>
#include <math.h>

// ============================================================================
// XCA transposed attention, bf16-MFMA, round 18:
//  - gemm_mfma: round-13 verbatim (best measured: 183us; dbuf + 1 barrier/iter).
//  - attn_fused: r13-style double-buffer on QK^T and PV loops (1 barrier/iter,
//    occupancy-free: 74KB still = 2 blocks/CU); V0 prefetch issued before
//    softmax so its latency hides under the VALU phase.
//  - dw3x3_l2norm: 8 rows/wave (10-row staging, read amp 1.5x -> 1.25x).
//  - transposes / cvt unchanged.
// ============================================================================

#define HW 65536
#define IMW 256

typedef short bf16x8 __attribute__((ext_vector_type(8)));
typedef float f32x4  __attribute__((ext_vector_type(4)));

__device__ __forceinline__ float bf2f(ushort u) {
    return __uint_as_float((uint)u << 16);
}
__device__ __forceinline__ ushort f2bf(float f) {
    uint i = __float_as_uint(f);
    return (ushort)((i + 0x7FFFu + ((i >> 16) & 1u)) >> 16);
}

__device__ __forceinline__ void gload16(const ushort* g, ushort* l) {
    __builtin_amdgcn_global_load_lds(
        (const __attribute__((address_space(1))) void*)g,
        (__attribute__((address_space(3))) void*)l,
        16, 0, 0);
}

// ---- flat fp32 -> bf16 (weights)
__global__ __launch_bounds__(256) void cvt_f32_bf16(const float* __restrict__ s,
                                                    ushort* __restrict__ d, int n)
{
    int i = blockIdx.x * 256 + threadIdx.x;
    if (i < n) d[i] = f2bf(s[i]);
}

// ---- fp32 [R][C] -> bf16 [C][R] transpose+convert, 64x64 tiles, z-sliced
__global__ __launch_bounds__(256) void cvt_transpose_f32(const float* __restrict__ src,
                                                         ushort* __restrict__ dst,
                                                         int R, int C,
                                                         long ssS, long ssD)
{
    __shared__ ushort Ls[64][72];
    int t = threadIdx.x;
    long z = blockIdx.z;
    src += z * ssS; dst += z * ssD;
    int c0 = blockIdx.x * 64, r0 = blockIdx.y * 64;
    {
        int r = t >> 2, cs = t & 3;
        const float* gp = src + (size_t)(r0 + r) * C + c0 + cs * 16;
        ushort tmp[16];
        #pragma unroll
        for (int q = 0; q < 4; ++q) {
            float4 v = *(const float4*)(gp + q * 4);
            tmp[q*4+0] = f2bf(v.x); tmp[q*4+1] = f2bf(v.y);
            tmp[q*4+2] = f2bf(v.z); tmp[q*4+3] = f2bf(v.w);
        }
        *(uint4*)&Ls[r][cs * 16]     = *(uint4*)&tmp[0];
        *(uint4*)&Ls[r][cs * 16 + 8] = *(uint4*)&tmp[8];
    }
    __syncthreads();
    {
        int cc = t & 63, seg = t >> 6;
        ushort tmp[16];
        #pragma unroll
        for (int j = 0; j < 16; ++j) tmp[j] = Ls[seg * 16 + j][cc];
        ushort* op = dst + (size_t)(c0 + cc) * R + r0 + seg * 16;
        *(uint4*)(op)     = *(uint4*)&tmp[0];
        *(uint4*)(op + 8) = *(uint4*)&tmp[8];
    }
}

// ---- bf16 [R][C] -> bf16 [C][R] transpose, 64x64 tiles, z-sliced
__global__ __launch_bounds__(256) void transpose_bf16(const ushort* __restrict__ src,
                                                      ushort* __restrict__ dst,
                                                      int R, int C,
                                                      long ssS, long ssD)
{
    __shared__ ushort Ls[64][72];
    int t = threadIdx.x;
    long z = blockIdx.z;
    src += z * ssS; dst += z * ssD;
    int c0 = blockIdx.x * 64, r0 = blockIdx.y * 64;
    {
        int r = t >> 2, cs = t & 3;
        const ushort* gp = src + (size_t)(r0 + r) * C + c0 + cs * 16;
        *(uint4*)&Ls[r][cs * 16]     = *(const uint4*)(gp);
        *(uint4*)&Ls[r][cs * 16 + 8] = *(const uint4*)(gp + 8);
    }
    __syncthreads();
    {
        int cc = t & 63, seg = t >> 6;
        ushort tmp[16];
        #pragma unroll
        for (int j = 0; j < 16; ++j) tmp[j] = Ls[seg * 16 + j][cc];
        ushort* op = dst + (size_t)(c0 + cc) * R + r0 + seg * 16;
        *(uint4*)(op)     = *(uint4*)&tmp[0];
        *(uint4*)(op + 8) = *(uint4*)&tmp[8];
    }
}

// ---- V [b][384+r][256][256] -> Vt [s=b*192+r][256][256]^T
__global__ __launch_bounds__(256) void transpose_v(const ushort* __restrict__ post,
                                                   ushort* __restrict__ vt)
{
    __shared__ ushort Ls[64][72];
    int t = threadIdx.x;
    int s = blockIdx.z;
    int b = s / 192, r = s - b * 192;
    const ushort* src = post + ((size_t)b * 576 + 384 + r) * HW;
    ushort*       dst = vt + (size_t)s * HW;
    int c0 = blockIdx.x * 64, r0 = blockIdx.y * 64;
    {
        int rr = t >> 2, cs = t & 3;
        const ushort* gp = src + (size_t)(r0 + rr) * IMW + c0 + cs * 16;
        *(uint4*)&Ls[rr][cs * 16]     = *(const uint4*)(gp);
        *(uint4*)&Ls[rr][cs * 16 + 8] = *(const uint4*)(gp + 8);
    }
    __syncthreads();
    {
        int cc = t & 63, seg = t >> 6;
        ushort tmp[16];
        #pragma unroll
        for (int j = 0; j < 16; ++j) tmp[j] = Ls[seg * 16 + j][cc];
        ushort* op = dst + (size_t)(c0 + cc) * IMW + r0 + seg * 16;
        *(uint4*)(op)     = *(uint4*)&tmp[0];
        *(uint4*)(op + 8) = *(uint4*)&tmp[8];
    }
}

// ---- MFMA GEMM (round-13 verbatim): dbuf LDS, gload_lds, 1 barrier/iter.
__global__ __launch_bounds__(256) void gemm_mfma(const ushort* __restrict__ A, int lda, long sliceA,
                                                 const ushort* __restrict__ B, int ldb, long sliceB,
                                                 void* __restrict__ Dp, int ldd, long sliceD,
                                                 const float* __restrict__ bias,
                                                 int K, int outF32, int NM, int NN)
{
    int lin = blockIdx.x;
    int r8 = lin & 7, kk_ = lin >> 3;
    int m = kk_ % NM, fg = kk_ / NM;
    int g = fg * 8 + r8;
    int nt_ = g % NN;
    long z = g / NN;
    int m0 = m * 64;
    int n0 = nt_ * 256;

    __shared__ ushort Ws[2][64][32];
    __shared__ ushort Xs[2][256][32];
    int t = threadIdx.x, wv = t >> 6, lane = t & 63;
    int fr = lane & 15, sg = lane >> 4;
    A += z * sliceA; B += z * sliceB;

    int rl   = wv * 16 + (lane >> 2);
    int chnk = (lane & 3) ^ ((lane >> 3) & 3);
    const ushort* srcA  = A + (size_t)(m0 + rl) * lda + chnk * 8;
    const ushort* srcB0 = B + (size_t)(n0 +       rl) * ldb + chnk * 8;
    const ushort* srcB1 = B + (size_t)(n0 +  64 + rl) * ldb + chnk * 8;
    const ushort* srcB2 = B + (size_t)(n0 + 128 + rl) * ldb + chnk * 8;
    const ushort* srcB3 = B + (size_t)(n0 + 192 + rl) * ldb + chnk * 8;

    int sp = sg ^ ((fr >> 1) & 3);

    f32x4 acc[4][4];
    #pragma unroll
    for (int i = 0; i < 4; ++i)
        #pragma unroll
        for (int j = 0; j < 4; ++j) acc[i][j] = (f32x4){0.f, 0.f, 0.f, 0.f};

    gload16(srcA,  &Ws[0][wv * 16][0]);
    gload16(srcB0, &Xs[0][      wv * 16][0]);
    gload16(srcB1, &Xs[0][ 64 + wv * 16][0]);
    gload16(srcB2, &Xs[0][128 + wv * 16][0]);
    gload16(srcB3, &Xs[0][192 + wv * 16][0]);
    __syncthreads();

    int nkit = K >> 5;
    for (int kit = 0; kit < nkit; ++kit) {
        int cur = kit & 1;
        if (kit + 1 < nkit) {
            int kn = (kit + 1) * 32;
            gload16(srcA  + kn, &Ws[cur ^ 1][wv * 16][0]);
            gload16(srcB0 + kn, &Xs[cur ^ 1][      wv * 16][0]);
            gload16(srcB1 + kn, &Xs[cur ^ 1][ 64 + wv * 16][0]);
            gload16(srcB2 + kn, &Xs[cur ^ 1][128 + wv * 16][0]);
            gload16(srcB3 + kn, &Xs[cur ^ 1][192 + wv * 16][0]);
        }
        bf16x8 a[4];
        #pragma unroll
        for (int i = 0; i < 4; ++i)
            a[i] = *(const bf16x8*)&Ws[cur][i * 16 + fr][sp * 8];
        #pragma unroll
        for (int j = 0; j < 4; ++j) {
            bf16x8 b = *(const bf16x8*)&Xs[cur][wv * 64 + j * 16 + fr][sp * 8];
            #pragma unroll
            for (int i = 0; i < 4; ++i)
                acc[i][j] = __builtin_amdgcn_mfma_f32_16x16x32_bf16(a[i], b, acc[i][j], 0, 0, 0);
        }
        __syncthreads();
    }

    int nw0 = n0 + wv * 64;
    int rbase = sg * 4;
    if (outF32) {
        float* D = (float*)Dp + z * sliceD;
        #pragma unroll
        for (int i = 0; i < 4; ++i) {
            #pragma unroll
            for (int r_ = 0; r_ < 4; ++r_) {
                int mrow = m0 + i * 16 + rbase + r_;
                float bv = bias ? bias[mrow] : 0.f;
                #pragma unroll
                for (int j = 0; j < 4; ++j)
                    D[(size_t)mrow * ldd + nw0 + j * 16 + fr] = acc[i][j][r_] + bv;
            }
        }
    } else {
        ushort* D = (ushort*)Dp + z * sliceD;
        #pragma unroll
        for (int i = 0; i < 4; ++i) {
            #pragma unroll
            for (int r_ = 0; r_ < 4; ++r_) {
                int mrow = m0 + i * 16 + rbase + r_;
                float bv = bias ? bias[mrow] : 0.f;
                #pragma unroll
                for (int j = 0; j < 4; ++j)
                    D[(size_t)mrow * ldd + nw0 + j * 16 + fr] = f2bf(acc[i][j][r_] + bv);
            }
        }
    }
}

// ---- fused attention: S=QK^T*t, softmax, O=P@Vt. Double-buffered (1 barrier
// per iter); V0 prefetch issued before softmax (latency hides under VALU).
__global__ __launch_bounds__(256) void attn_fused(const ushort* __restrict__ post,
                                                  const ushort* __restrict__ vt,
                                                  const float* __restrict__ temp,
                                                  ushort* __restrict__ O)
{
    __shared__ ushort Ws[2][64][32];     // Q dbuf
    __shared__ ushort Xs[2][256][32];    // K / Vt dbuf
    __shared__ ushort Ps[64][264];       // P (bf16)
    int t = threadIdx.x, wv = t >> 6, lane = t & 63;
    int fr = lane & 15, sg = lane >> 4;
    int lin = blockIdx.x;
    int r8 = lin & 7, k_ = lin >> 3;
    int mtile = k_ & 3, fg = k_ >> 2;
    int s = fg * 8 + r8;
    int b = s / 192, ch = s - b * 192;
    const ushort* Aq = post + ((size_t)b * 576 + ch) * HW;
    const ushort* Bk = Aq + (size_t)192 * HW;
    const ushort* Vt = vt + (size_t)s * HW;
    int m0 = mtile * 64;

    int rl   = wv * 16 + (lane >> 2);
    int chnk = (lane & 3) ^ ((lane >> 3) & 3);
    int sp   = sg ^ ((fr >> 1) & 3);
    const ushort* srcQ  = Aq + (size_t)(m0 + rl) * IMW + chnk * 8;
    const ushort* srcK0 = Bk + (size_t)(      rl) * IMW + chnk * 8;
    const ushort* srcK1 = Bk + (size_t)( 64 + rl) * IMW + chnk * 8;
    const ushort* srcK2 = Bk + (size_t)(128 + rl) * IMW + chnk * 8;
    const ushort* srcK3 = Bk + (size_t)(192 + rl) * IMW + chnk * 8;
    const ushort* srcV0 = Vt + (size_t)(      rl) * IMW + chnk * 8;
    const ushort* srcV1 = Vt + (size_t)( 64 + rl) * IMW + chnk * 8;
    const ushort* srcV2 = Vt + (size_t)(128 + rl) * IMW + chnk * 8;
    const ushort* srcV3 = Vt + (size_t)(192 + rl) * IMW + chnk * 8;

    f32x4 acc[16];
    #pragma unroll
    for (int i = 0; i < 16; ++i) acc[i] = (f32x4){0.f, 0.f, 0.f, 0.f};

    // ---- phase 1: QK^T, dbuf, 1 barrier/iter
    gload16(srcQ,  &Ws[0][wv * 16][0]);
    gload16(srcK0, &Xs[0][      wv * 16][0]);
    gload16(srcK1, &Xs[0][ 64 + wv * 16][0]);
    gload16(srcK2, &Xs[0][128 + wv * 16][0]);
    gload16(srcK3, &Xs[0][192 + wv * 16][0]);
    __syncthreads();

    for (int kit = 0; kit < 8; ++kit) {
        int cur = kit & 1;
        if (kit < 7) {
            int kn = (kit + 1) * 32;
            gload16(srcQ  + kn, &Ws[cur ^ 1][wv * 16][0]);
            gload16(srcK0 + kn, &Xs[cur ^ 1][      wv * 16][0]);
            gload16(srcK1 + kn, &Xs[cur ^ 1][ 64 + wv * 16][0]);
            gload16(srcK2 + kn, &Xs[cur ^ 1][128 + wv * 16][0]);
            gload16(srcK3 + kn, &Xs[cur ^ 1][192 + wv * 16][0]);
        }
        bf16x8 a = *(const bf16x8*)&Ws[cur][wv * 16 + fr][sp * 8];
        #pragma unroll
        for (int nt = 0; nt < 16; ++nt) {
            bf16x8 bfrag = *(const bf16x8*)&Xs[cur][nt * 16 + fr][sp * 8];
            acc[nt] = __builtin_amdgcn_mfma_f32_16x16x32_bf16(a, bfrag, acc[nt], 0, 0, 0);
        }
        __syncthreads();
    }

    // ---- prefetch V tile 0 (lands during softmax)
    gload16(srcV0, &Xs[0][      wv * 16][0]);
    gload16(srcV1, &Xs[0][ 64 + wv * 16][0]);
    gload16(srcV2, &Xs[0][128 + wv * 16][0]);
    gload16(srcV3, &Xs[0][192 + wv * 16][0]);

    // ---- phase 2: softmax (in-register, 16-lane groups), P -> LDS bf16
    float tv = temp[ch >> 5];
    #pragma unroll
    for (int r_ = 0; r_ < 4; ++r_) {
        float v[16];
        float mx = -3.4e38f;
        #pragma unroll
        for (int nt = 0; nt < 16; ++nt) { v[nt] = acc[nt][r_] * tv; mx = fmaxf(mx, v[nt]); }
        #pragma unroll
        for (int sh = 1; sh < 16; sh <<= 1) mx = fmaxf(mx, __shfl_xor(mx, sh, 64));
        float sum = 0.f;
        #pragma unroll
        for (int nt = 0; nt < 16; ++nt) { v[nt] = __expf(v[nt] - mx); sum += v[nt]; }
        #pragma unroll
        for (int sh = 1; sh < 16; sh <<= 1) sum += __shfl_xor(sum, sh, 64);
        float inv = 1.f / sum;
        int ml = wv * 16 + sg * 4 + r_;
        #pragma unroll
        for (int nt = 0; nt < 16; ++nt)
            Ps[ml][fr + nt * 16] = f2bf(v[nt] * inv);
    }
    __syncthreads();   // drains V0 prefetch

    // ---- phase 3: O = P @ Vt, dbuf, 1 barrier/iter
    f32x4 acc2[16];
    #pragma unroll
    for (int i = 0; i < 16; ++i) acc2[i] = (f32x4){0.f, 0.f, 0.f, 0.f};

    for (int y = 0; y < 8; ++y) {
        int cur = y & 1;
        if (y < 7) {
            int yn = (y + 1) * 32;
            gload16(srcV0 + yn, &Xs[cur ^ 1][      wv * 16][0]);
            gload16(srcV1 + yn, &Xs[cur ^ 1][ 64 + wv * 16][0]);
            gload16(srcV2 + yn, &Xs[cur ^ 1][128 + wv * 16][0]);
            gload16(srcV3 + yn, &Xs[cur ^ 1][192 + wv * 16][0]);
        }
        bf16x8 a = *(const bf16x8*)&Ps[wv * 16 + fr][y * 32 + sg * 8];
        #pragma unroll
        for (int nt = 0; nt < 16; ++nt) {
            bf16x8 bfrag = *(const bf16x8*)&Xs[cur][nt * 16 + fr][sp * 8];
            acc2[nt] = __builtin_amdgcn_mfma_f32_16x16x32_bf16(a, bfrag, acc2[nt], 0, 0, 0);
        }
        __syncthreads();
    }

    ushort* Op = O + (size_t)s * HW;
    int mrow = m0 + wv * 16 + sg * 4;
    #pragma unroll
    for (int r_ = 0; r_ < 4; ++r_) {
        #pragma unroll
        for (int nt = 0; nt < 16; ++nt)
            Op[(size_t)(mrow + r_) * IMW + fr + nt * 16] = f2bf(acc2[nt][r_]);
    }
}

// ---- depthwise 3x3 SAME + fused L2 row-norm. 8 output rows per wave
// (stage rows r0-1 .. r0+8). grid (8, 576, 4).
__global__ __launch_bounds__(256) void dw3x3_l2norm(const ushort* __restrict__ in,
                                                    const float* __restrict__ w,
                                                    const float* __restrict__ bias,
                                                    ushort* __restrict__ out)
{
    int t = threadIdx.x;
    int lane = t & 63, wv = t >> 6;
    int ch = blockIdx.y;
    int r0 = blockIdx.x * 32 + wv * 8;
    const ushort* img  = in  + ((size_t)blockIdx.z * 576 + ch) * HW;
    ushort*       outp = out + ((size_t)blockIdx.z * 576 + ch) * HW;
    int px = lane * 4;

    float rv[10][4], lv[10], rx[10];
    #pragma unroll
    for (int i = 0; i < 10; ++i) {
        int rr = r0 - 1 + i;
        if ((unsigned)rr <= 255u) {
            ushort4 cv = *(const ushort4*)&img[(size_t)rr * IMW + px];
            rv[i][0] = bf2f(cv.x); rv[i][1] = bf2f(cv.y);
            rv[i][2] = bf2f(cv.z); rv[i][3] = bf2f(cv.w);
        } else {
            rv[i][0] = rv[i][1] = rv[i][2] = rv[i][3] = 0.f;
        }
        float l = __shfl_up(rv[i][3], 1, 64);
        lv[i] = (lane == 0) ? 0.f : l;
        float r = __shfl_down(rv[i][0], 1, 64);
        rx[i] = (lane == 63) ? 0.f : r;
    }

    const float* wch = w + ch * 9;
    float bv = bias[ch];
    bool do_norm = (ch < 384);

    #pragma unroll
    for (int j = 0; j < 8; ++j) {
        float a0 = bv, a1 = bv, a2 = bv, a3 = bv;
        #pragma unroll
        for (int dy = 0; dy < 3; ++dy) {
            int i = j + dy;
            float w0 = wch[dy * 3], w1 = wch[dy * 3 + 1], w2 = wch[dy * 3 + 2];
            a0 += lv[i]    * w0 + rv[i][0] * w1 + rv[i][1] * w2;
            a1 += rv[i][0] * w0 + rv[i][1] * w1 + rv[i][2] * w2;
            a2 += rv[i][1] * w0 + rv[i][2] * w1 + rv[i][3] * w2;
            a3 += rv[i][2] * w0 + rv[i][3] * w1 + rx[i]    * w2;
        }
        if (do_norm) {
            float ss = a0 * a0 + a1 * a1 + a2 * a2 + a3 * a3;
            #pragma unroll
            for (int m = 1; m < 64; m <<= 1) ss += __shfl_xor(ss, m, 64);
            float inv = 1.0f / fmaxf(sqrtf(ss), 1e-12f);
            a0 *= inv; a1 *= inv; a2 *= inv; a3 *= inv;
        }
        ushort4 o;
        o.x = f2bf(a0); o.y = f2bf(a1); o.z = f2bf(a2); o.w = f2bf(a3);
        *(ushort4*)&outp[(size_t)(r0 + j) * IMW + px] = o;
    }
}

extern "C" void kernel_launch(void* const* d_in, const int* in_sizes, int n_in,
                              void* d_out, int out_size, void* d_ws, size_t ws_size,
                              hipStream_t stream)
{
    const float* x      = (const float*)d_in[0];
    const float* qkv_w  = (const float*)d_in[1];
    const float* qkv_b  = (const float*)d_in[2];
    const float* dw_w   = (const float*)d_in[3];
    const float* dw_b   = (const float*)d_in[4];
    const float* proj_w = (const float*)d_in[5];
    const float* proj_b = (const float*)d_in[6];
    const float* temp   = (const float*)d_in[7];
    float* out = (float*)d_out;

    const size_t off_wq   = 0;
    const size_t off_wp   = 110592;
    const size_t off_pre  = 262144;
    const size_t off_post = off_pre + (size_t)4 * 576 * HW;
    const size_t off_xt   = off_post + (size_t)4 * 576 * HW;
    const size_t total_us = off_xt + (size_t)4 * 192 * HW;
    if (ws_size < total_us * sizeof(ushort)) return;

    ushort* wsb  = (ushort*)d_ws;
    ushort* wq   = wsb + off_wq;
    ushort* wp   = wsb + off_wp;
    ushort* pre  = wsb + off_pre;
    ushort* post = wsb + off_post;
    ushort* xt   = wsb + off_xt;
    ushort* Obuf = pre;
    ushort* Otb  = pre + (size_t)4 * 192 * HW;

    const long SL = (long)192 * HW;

    cvt_f32_bf16<<<dim3(432), 256, 0, stream>>>(qkv_w, wq, 110592);
    cvt_f32_bf16<<<dim3(144), 256, 0, stream>>>(proj_w, wp, 36864);

    cvt_transpose_f32<<<dim3(1024, 3, 4), 256, 0, stream>>>(x, xt, 192, HW, SL, SL);
    // qkv: NM=9, NN=256, 4 batches -> 9216 blocks
    gemm_mfma<<<dim3(9 * 256 * 4), 256, 0, stream>>>(wq, 192, 0, xt, 192, SL,
                                                     pre, HW, (long)576 * HW,
                                                     qkv_b, 192, 0, 9, 256);
    dw3x3_l2norm<<<dim3(8, 576, 4), 256, 0, stream>>>(pre, dw_w, dw_b, post);
    transpose_v<<<dim3(4, 4, 768), 256, 0, stream>>>(post, xt);
    attn_fused<<<dim3(4 * 768), 256, 0, stream>>>(post, xt, temp, Obuf);
    transpose_bf16<<<dim3(1024, 3, 4), 256, 0, stream>>>(Obuf, Otb, 192, HW, SL, SL);
    // proj: NM=3, NN=256, 4 batches -> 3072 blocks
    gemm_mfma<<<dim3(3 * 256 * 4), 256, 0, stream>>>(wp, 192, 0, Otb, 192, SL,
                                                     out, HW, SL,
                                                     proj_b, 192, 1, 3, 256);
}

// Round 20
// 702.812 us; speedup vs baseline: 1.0898x; 1.0224x over previous
//
#include <hip/hip_runtime.h>
#include <hip/hip_bf16.h>
#include <math.h>

// ============================================================================
// XCA transposed attention, bf16-MFMA, round 19:
//  - dw3x3_l2norm: reverted to 4-rows/wave (proven r13 body) + FUSED V
//    transpose: for ch>=384 the 16x256 output tile goes through LDS and is
//    written directly as Vt[s][w][h] (32B contiguous per thread). The
//    separate transpose_v kernel is removed.
//  - gemm_mfma: round-13 verbatim (best measured).
//  - attn_fused: round-18 dbuf version (kept; neutral-positive).
//  - transposes / cvt unchanged.
// ============================================================================

#define HW 65536
#define IMW 256

typedef short bf16x8 __attribute__((ext_vector_type(8)));
typedef float f32x4  __attribute__((ext_vector_type(4)));

__device__ __forceinline__ float bf2f(ushort u) {
    return __uint_as_float((uint)u << 16);
}
__device__ __forceinline__ ushort f2bf(float f) {
    uint i = __float_as_uint(f);
    return (ushort)((i + 0x7FFFu + ((i >> 16) & 1u)) >> 16);
}

__device__ __forceinline__ void gload16(const ushort* g, ushort* l) {
    __builtin_amdgcn_global_load_lds(
        (const __attribute__((address_space(1))) void*)g,
        (__attribute__((address_space(3))) void*)l,
        16, 0, 0);
}

// ---- flat fp32 -> bf16 (weights)
__global__ __launch_bounds__(256) void cvt_f32_bf16(const float* __restrict__ s,
                                                    ushort* __restrict__ d, int n)
{
    int i = blockIdx.x * 256 + threadIdx.x;
    if (i < n) d[i] = f2bf(s[i]);
}

// ---- fp32 [R][C] -> bf16 [C][R] transpose+convert, 64x64 tiles, z-sliced
__global__ __launch_bounds__(256) void cvt_transpose_f32(const float* __restrict__ src,
                                                         ushort* __restrict__ dst,
                                                         int R, int C,
                                                         long ssS, long ssD)
{
    __shared__ ushort Ls[64][72];
    int t = threadIdx.x;
    long z = blockIdx.z;
    src += z * ssS; dst += z * ssD;
    int c0 = blockIdx.x * 64, r0 = blockIdx.y * 64;
    {
        int r = t >> 2, cs = t & 3;
        const float* gp = src + (size_t)(r0 + r) * C + c0 + cs * 16;
        ushort tmp[16];
        #pragma unroll
        for (int q = 0; q < 4; ++q) {
            float4 v = *(const float4*)(gp + q * 4);
            tmp[q*4+0] = f2bf(v.x); tmp[q*4+1] = f2bf(v.y);
            tmp[q*4+2] = f2bf(v.z); tmp[q*4+3] = f2bf(v.w);
        }
        *(uint4*)&Ls[r][cs * 16]     = *(uint4*)&tmp[0];
        *(uint4*)&Ls[r][cs * 16 + 8] = *(uint4*)&tmp[8];
    }
    __syncthreads();
    {
        int cc = t & 63, seg = t >> 6;
        ushort tmp[16];
        #pragma unroll
        for (int j = 0; j < 16; ++j) tmp[j] = Ls[seg * 16 + j][cc];
        ushort* op = dst + (size_t)(c0 + cc) * R + r0 + seg * 16;
        *(uint4*)(op)     = *(uint4*)&tmp[0];
        *(uint4*)(op + 8) = *(uint4*)&tmp[8];
    }
}

// ---- bf16 [R][C] -> bf16 [C][R] transpose, 64x64 tiles, z-sliced
__global__ __launch_bounds__(256) void transpose_bf16(const ushort* __restrict__ src,
                                                      ushort* __restrict__ dst,
                                                      int R, int C,
                                                      long ssS, long ssD)
{
    __shared__ ushort Ls[64][72];
    int t = threadIdx.x;
    long z = blockIdx.z;
    src += z * ssS; dst += z * ssD;
    int c0 = blockIdx.x * 64, r0 = blockIdx.y * 64;
    {
        int r = t >> 2, cs = t & 3;
        const ushort* gp = src + (size_t)(r0 + r) * C + c0 + cs * 16;
        *(uint4*)&Ls[r][cs * 16]     = *(const uint4*)(gp);
        *(uint4*)&Ls[r][cs * 16 + 8] = *(const uint4*)(gp + 8);
    }
    __syncthreads();
    {
        int cc = t & 63, seg = t >> 6;
        ushort tmp[16];
        #pragma unroll
        for (int j = 0; j < 16; ++j) tmp[j] = Ls[seg * 16 + j][cc];
        ushort* op = dst + (size_t)(c0 + cc) * R + r0 + seg * 16;
        *(uint4*)(op)     = *(uint4*)&tmp[0];
        *(uint4*)(op + 8) = *(uint4*)&tmp[8];
    }
}

// ---- MFMA GEMM (round-13 verbatim): dbuf LDS, gload_lds, 1 barrier/iter.
__global__ __launch_bounds__(256) void gemm_mfma(const ushort* __restrict__ A, int lda, long sliceA,
                                                 const ushort* __restrict__ B, int ldb, long sliceB,
                                                 void* __restrict__ Dp, int ldd, long sliceD,
                                                 const float* __restrict__ bias,
                                                 int K, int outF32, int NM, int NN)
{
    int lin = blockIdx.x;
    int r8 = lin & 7, kk_ = lin >> 3;
    int m = kk_ % NM, fg = kk_ / NM;
    int g = fg * 8 + r8;
    int nt_ = g % NN;
    long z = g / NN;
    int m0 = m * 64;
    int n0 = nt_ * 256;

    __shared__ ushort Ws[2][64][32];
    __shared__ ushort Xs[2][256][32];
    int t = threadIdx.x, wv = t >> 6, lane = t & 63;
    int fr = lane & 15, sg = lane >> 4;
    A += z * sliceA; B += z * sliceB;

    int rl   = wv * 16 + (lane >> 2);
    int chnk = (lane & 3) ^ ((lane >> 3) & 3);
    const ushort* srcA  = A + (size_t)(m0 + rl) * lda + chnk * 8;
    const ushort* srcB0 = B + (size_t)(n0 +       rl) * ldb + chnk * 8;
    const ushort* srcB1 = B + (size_t)(n0 +  64 + rl) * ldb + chnk * 8;
    const ushort* srcB2 = B + (size_t)(n0 + 128 + rl) * ldb + chnk * 8;
    const ushort* srcB3 = B + (size_t)(n0 + 192 + rl) * ldb + chnk * 8;

    int sp = sg ^ ((fr >> 1) & 3);

    f32x4 acc[4][4];
    #pragma unroll
    for (int i = 0; i < 4; ++i)
        #pragma unroll
        for (int j = 0; j < 4; ++j) acc[i][j] = (f32x4){0.f, 0.f, 0.f, 0.f};

    gload16(srcA,  &Ws[0][wv * 16][0]);
    gload16(srcB0, &Xs[0][      wv * 16][0]);
    gload16(srcB1, &Xs[0][ 64 + wv * 16][0]);
    gload16(srcB2, &Xs[0][128 + wv * 16][0]);
    gload16(srcB3, &Xs[0][192 + wv * 16][0]);
    __syncthreads();

    int nkit = K >> 5;
    for (int kit = 0; kit < nkit; ++kit) {
        int cur = kit & 1;
        if (kit + 1 < nkit) {
            int kn = (kit + 1) * 32;
            gload16(srcA  + kn, &Ws[cur ^ 1][wv * 16][0]);
            gload16(srcB0 + kn, &Xs[cur ^ 1][      wv * 16][0]);
            gload16(srcB1 + kn, &Xs[cur ^ 1][ 64 + wv * 16][0]);
            gload16(srcB2 + kn, &Xs[cur ^ 1][128 + wv * 16][0]);
            gload16(srcB3 + kn, &Xs[cur ^ 1][192 + wv * 16][0]);
        }
        bf16x8 a[4];
        #pragma unroll
        for (int i = 0; i < 4; ++i)
            a[i] = *(const bf16x8*)&Ws[cur][i * 16 + fr][sp * 8];
        #pragma unroll
        for (int j = 0; j < 4; ++j) {
            bf16x8 b = *(const bf16x8*)&Xs[cur][wv * 64 + j * 16 + fr][sp * 8];
            #pragma unroll
            for (int i = 0; i < 4; ++i)
                acc[i][j] = __builtin_amdgcn_mfma_f32_16x16x32_bf16(a[i], b, acc[i][j], 0, 0, 0);
        }
        __syncthreads();
    }

    int nw0 = n0 + wv * 64;
    int rbase = sg * 4;
    if (outF32) {
        float* D = (float*)Dp + z * sliceD;
        #pragma unroll
        for (int i = 0; i < 4; ++i) {
            #pragma unroll
            for (int r_ = 0; r_ < 4; ++r_) {
                int mrow = m0 + i * 16 + rbase + r_;
                float bv = bias ? bias[mrow] : 0.f;
                #pragma unroll
                for (int j = 0; j < 4; ++j)
                    D[(size_t)mrow * ldd + nw0 + j * 16 + fr] = acc[i][j][r_] + bv;
            }
        }
    } else {
        ushort* D = (ushort*)Dp + z * sliceD;
        #pragma unroll
        for (int i = 0; i < 4; ++i) {
            #pragma unroll
            for (int r_ = 0; r_ < 4; ++r_) {
                int mrow = m0 + i * 16 + rbase + r_;
                float bv = bias ? bias[mrow] : 0.f;
                #pragma unroll
                for (int j = 0; j < 4; ++j)
                    D[(size_t)mrow * ldd + nw0 + j * 16 + fr] = f2bf(acc[i][j][r_] + bv);
            }
        }
    }
}

// ---- fused attention (round-18): dbuf, 1 barrier/iter, V0 prefetch under softmax
__global__ __launch_bounds__(256) void attn_fused(const ushort* __restrict__ post,
                                                  const ushort* __restrict__ vt,
                                                  const float* __restrict__ temp,
                                                  ushort* __restrict__ O)
{
    __shared__ ushort Ws[2][64][32];
    __shared__ ushort Xs[2][256][32];
    __shared__ ushort Ps[64][264];
    int t = threadIdx.x, wv = t >> 6, lane = t & 63;
    int fr = lane & 15, sg = lane >> 4;
    int lin = blockIdx.x;
    int r8 = lin & 7, k_ = lin >> 3;
    int mtile = k_ & 3, fg = k_ >> 2;
    int s = fg * 8 + r8;
    int b = s / 192, ch = s - b * 192;
    const ushort* Aq = post + ((size_t)b * 576 + ch) * HW;
    const ushort* Bk = Aq + (size_t)192 * HW;
    const ushort* Vt = vt + (size_t)s * HW;
    int m0 = mtile * 64;

    int rl   = wv * 16 + (lane >> 2);
    int chnk = (lane & 3) ^ ((lane >> 3) & 3);
    int sp   = sg ^ ((fr >> 1) & 3);
    const ushort* srcQ  = Aq + (size_t)(m0 + rl) * IMW + chnk * 8;
    const ushort* srcK0 = Bk + (size_t)(      rl) * IMW + chnk * 8;
    const ushort* srcK1 = Bk + (size_t)( 64 + rl) * IMW + chnk * 8;
    const ushort* srcK2 = Bk + (size_t)(128 + rl) * IMW + chnk * 8;
    const ushort* srcK3 = Bk + (size_t)(192 + rl) * IMW + chnk * 8;
    const ushort* srcV0 = Vt + (size_t)(      rl) * IMW + chnk * 8;
    const ushort* srcV1 = Vt + (size_t)( 64 + rl) * IMW + chnk * 8;
    const ushort* srcV2 = Vt + (size_t)(128 + rl) * IMW + chnk * 8;
    const ushort* srcV3 = Vt + (size_t)(192 + rl) * IMW + chnk * 8;

    f32x4 acc[16];
    #pragma unroll
    for (int i = 0; i < 16; ++i) acc[i] = (f32x4){0.f, 0.f, 0.f, 0.f};

    gload16(srcQ,  &Ws[0][wv * 16][0]);
    gload16(srcK0, &Xs[0][      wv * 16][0]);
    gload16(srcK1, &Xs[0][ 64 + wv * 16][0]);
    gload16(srcK2, &Xs[0][128 + wv * 16][0]);
    gload16(srcK3, &Xs[0][192 + wv * 16][0]);
    __syncthreads();

    for (int kit = 0; kit < 8; ++kit) {
        int cur = kit & 1;
        if (kit < 7) {
            int kn = (kit + 1) * 32;
            gload16(srcQ  + kn, &Ws[cur ^ 1][wv * 16][0]);
            gload16(srcK0 + kn, &Xs[cur ^ 1][      wv * 16][0]);
            gload16(srcK1 + kn, &Xs[cur ^ 1][ 64 + wv * 16][0]);
            gload16(srcK2 + kn, &Xs[cur ^ 1][128 + wv * 16][0]);
            gload16(srcK3 + kn, &Xs[cur ^ 1][192 + wv * 16][0]);
        }
        bf16x8 a = *(const bf16x8*)&Ws[cur][wv * 16 + fr][sp * 8];
        #pragma unroll
        for (int nt = 0; nt < 16; ++nt) {
            bf16x8 bfrag = *(const bf16x8*)&Xs[cur][nt * 16 + fr][sp * 8];
            acc[nt] = __builtin_amdgcn_mfma_f32_16x16x32_bf16(a, bfrag, acc[nt], 0, 0, 0);
        }
        __syncthreads();
    }

    gload16(srcV0, &Xs[0][      wv * 16][0]);
    gload16(srcV1, &Xs[0][ 64 + wv * 16][0]);
    gload16(srcV2, &Xs[0][128 + wv * 16][0]);
    gload16(srcV3, &Xs[0][192 + wv * 16][0]);

    float tv = temp[ch >> 5];
    #pragma unroll
    for (int r_ = 0; r_ < 4; ++r_) {
        float v[16];
        float mx = -3.4e38f;
        #pragma unroll
        for (int nt = 0; nt < 16; ++nt) { v[nt] = acc[nt][r_] * tv; mx = fmaxf(mx, v[nt]); }
        #pragma unroll
        for (int sh = 1; sh < 16; sh <<= 1) mx = fmaxf(mx, __shfl_xor(mx, sh, 64));
        float sum = 0.f;
        #pragma unroll
        for (int nt = 0; nt < 16; ++nt) { v[nt] = __expf(v[nt] - mx); sum += v[nt]; }
        #pragma unroll
        for (int sh = 1; sh < 16; sh <<= 1) sum += __shfl_xor(sum, sh, 64);
        float inv = 1.f / sum;
        int ml = wv * 16 + sg * 4 + r_;
        #pragma unroll
        for (int nt = 0; nt < 16; ++nt)
            Ps[ml][fr + nt * 16] = f2bf(v[nt] * inv);
    }
    __syncthreads();

    f32x4 acc2[16];
    #pragma unroll
    for (int i = 0; i < 16; ++i) acc2[i] = (f32x4){0.f, 0.f, 0.f, 0.f};

    for (int y = 0; y < 8; ++y) {
        int cur = y & 1;
        if (y < 7) {
            int yn = (y + 1) * 32;
            gload16(srcV0 + yn, &Xs[cur ^ 1][      wv * 16][0]);
            gload16(srcV1 + yn, &Xs[cur ^ 1][ 64 + wv * 16][0]);
            gload16(srcV2 + yn, &Xs[cur ^ 1][128 + wv * 16][0]);
            gload16(srcV3 + yn, &Xs[cur ^ 1][192 + wv * 16][0]);
        }
        bf16x8 a = *(const bf16x8*)&Ps[wv * 16 + fr][y * 32 + sg * 8];
        #pragma unroll
        for (int nt = 0; nt < 16; ++nt) {
            bf16x8 bfrag = *(const bf16x8*)&Xs[cur][nt * 16 + fr][sp * 8];
            acc2[nt] = __builtin_amdgcn_mfma_f32_16x16x32_bf16(a, bfrag, acc2[nt], 0, 0, 0);
        }
        __syncthreads();
    }

    ushort* Op = O + (size_t)s * HW;
    int mrow = m0 + wv * 16 + sg * 4;
    #pragma unroll
    for (int r_ = 0; r_ < 4; ++r_) {
        #pragma unroll
        for (int nt = 0; nt < 16; ++nt)
            Op[(size_t)(mrow + r_) * IMW + fr + nt * 16] = f2bf(acc2[nt][r_]);
    }
}

// ---- depthwise 3x3 SAME + fused L2 row-norm (4 rows/wave, proven) + fused
// V transpose: ch<384 -> post[ch][h][w]; ch>=384 -> Vt[s][w][h] via LDS tile.
// grid (16, 576, 4); branch is block-uniform (one ch per block).
__global__ __launch_bounds__(256) void dw3x3_l2norm(const ushort* __restrict__ in,
                                                    const float* __restrict__ w,
                                                    const float* __restrict__ bias,
                                                    ushort* __restrict__ out,
                                                    ushort* __restrict__ vt)
{
    __shared__ ushort Tls[16][264];
    int t = threadIdx.x;
    int lane = t & 63, wv = t >> 6;
    int ch = blockIdx.y;
    int b  = blockIdx.z;
    int h0 = blockIdx.x * 16;
    int r0 = h0 + wv * 4;
    const ushort* img = in + ((size_t)b * 576 + ch) * HW;
    int px = lane * 4;

    float rv[6][4], lv[6], rx[6];
    #pragma unroll
    for (int i = 0; i < 6; ++i) {
        int rr = r0 - 1 + i;
        if ((unsigned)rr <= 255u) {
            ushort4 cv = *(const ushort4*)&img[(size_t)rr * IMW + px];
            rv[i][0] = bf2f(cv.x); rv[i][1] = bf2f(cv.y);
            rv[i][2] = bf2f(cv.z); rv[i][3] = bf2f(cv.w);
        } else {
            rv[i][0] = rv[i][1] = rv[i][2] = rv[i][3] = 0.f;
        }
        float l = __shfl_up(rv[i][3], 1, 64);
        lv[i] = (lane == 0) ? 0.f : l;
        float r = __shfl_down(rv[i][0], 1, 64);
        rx[i] = (lane == 63) ? 0.f : r;
    }

    const float* wch = w + ch * 9;
    float bv = bias[ch];
    bool is_qk = (ch < 384);
    ushort* outp = out + ((size_t)b * 576 + ch) * HW;

    #pragma unroll
    for (int j = 0; j < 4; ++j) {
        float a0 = bv, a1 = bv, a2 = bv, a3 = bv;
        #pragma unroll
        for (int dy = 0; dy < 3; ++dy) {
            int i = j + dy;
            float w0 = wch[dy * 3], w1 = wch[dy * 3 + 1], w2 = wch[dy * 3 + 2];
            a0 += lv[i]    * w0 + rv[i][0] * w1 + rv[i][1] * w2;
            a1 += rv[i][0] * w0 + rv[i][1] * w1 + rv[i][2] * w2;
            a2 += rv[i][1] * w0 + rv[i][2] * w1 + rv[i][3] * w2;
            a3 += rv[i][2] * w0 + rv[i][3] * w1 + rx[i]    * w2;
        }
        if (is_qk) {
            float ss = a0 * a0 + a1 * a1 + a2 * a2 + a3 * a3;
            #pragma unroll
            for (int m = 1; m < 64; m <<= 1) ss += __shfl_xor(ss, m, 64);
            float inv = 1.0f / fmaxf(sqrtf(ss), 1e-12f);
            a0 *= inv; a1 *= inv; a2 *= inv; a3 *= inv;
        }
        ushort4 o;
        o.x = f2bf(a0); o.y = f2bf(a1); o.z = f2bf(a2); o.w = f2bf(a3);
        if (is_qk) {
            *(ushort4*)&outp[(size_t)(r0 + j) * IMW + px] = o;
        } else {
            *(ushort4*)&Tls[wv * 4 + j][px] = o;
        }
    }

    if (!is_qk) {   // block-uniform branch: transpose 16x256 tile -> Vt[s][w][h]
        __syncthreads();
        int s = b * 192 + ch - 384;
        ushort tmp[16];
        #pragma unroll
        for (int r = 0; r < 16; ++r) tmp[r] = Tls[r][t];
        ushort* op = vt + (size_t)s * HW + (size_t)t * IMW + h0;
        *(uint4*)(op)     = *(uint4*)&tmp[0];
        *(uint4*)(op + 8) = *(uint4*)&tmp[8];
    }
}

extern "C" void kernel_launch(void* const* d_in, const int* in_sizes, int n_in,
                              void* d_out, int out_size, void* d_ws, size_t ws_size,
                              hipStream_t stream)
{
    const float* x      = (const float*)d_in[0];
    const float* qkv_w  = (const float*)d_in[1];
    const float* qkv_b  = (const float*)d_in[2];
    const float* dw_w   = (const float*)d_in[3];
    const float* dw_b   = (const float*)d_in[4];
    const float* proj_w = (const float*)d_in[5];
    const float* proj_b = (const float*)d_in[6];
    const float* temp   = (const float*)d_in[7];
    float* out = (float*)d_out;

    const size_t off_wq   = 0;
    const size_t off_wp   = 110592;
    const size_t off_pre  = 262144;
    const size_t off_post = off_pre + (size_t)4 * 576 * HW;
    const size_t off_xt   = off_post + (size_t)4 * 576 * HW;
    const size_t total_us = off_xt + (size_t)4 * 192 * HW;
    if (ws_size < total_us * sizeof(ushort)) return;

    ushort* wsb  = (ushort*)d_ws;
    ushort* wq   = wsb + off_wq;
    ushort* wp   = wsb + off_wp;
    ushort* pre  = wsb + off_pre;
    ushort* post = wsb + off_post;
    ushort* xt   = wsb + off_xt;      // Xt for qkv gemm; then Vt (written by dw)
    ushort* Obuf = pre;
    ushort* Otb  = pre + (size_t)4 * 192 * HW;

    const long SL = (long)192 * HW;

    cvt_f32_bf16<<<dim3(432), 256, 0, stream>>>(qkv_w, wq, 110592);
    cvt_f32_bf16<<<dim3(144), 256, 0, stream>>>(proj_w, wp, 36864);

    cvt_transpose_f32<<<dim3(1024, 3, 4), 256, 0, stream>>>(x, xt, 192, HW, SL, SL);
    // qkv: NM=9, NN=256, 4 batches -> 9216 blocks
    gemm_mfma<<<dim3(9 * 256 * 4), 256, 0, stream>>>(wq, 192, 0, xt, 192, SL,
                                                     pre, HW, (long)576 * HW,
                                                     qkv_b, 192, 0, 9, 256);
    // dw + l2norm + fused V transpose (writes Vt into xt region; Xt is dead)
    dw3x3_l2norm<<<dim3(16, 576, 4), 256, 0, stream>>>(pre, dw_w, dw_b, post, xt);
    attn_fused<<<dim3(4 * 768), 256, 0, stream>>>(post, xt, temp, Obuf);
    transpose_bf16<<<dim3(1024, 3, 4), 256, 0, stream>>>(Obuf, Otb, 192, HW, SL, SL);
    // proj: NM=3, NN=256, 4 batches -> 3072 blocks
    gemm_mfma<<<dim3(3 * 256 * 4), 256, 0, stream>>>(wp, 192, 0, Otb, 192, SL,
                                                     out, HW, SL,
                                                     proj_b, 192, 1, 3, 256);
}

// Round 22
// 692.258 us; speedup vs baseline: 1.1064x; 1.0152x over previous
//
#include <hip/hip_runtime.h>
#include <hip/hip_bf16.h>
#include <math.h>

// ============================================================================
// XCA transposed attention, bf16-MFMA, round 21:
//  - round-20 kernel set with the bf16-epilogue store mapping FIXED:
//    row = pass*16 + (t>>4), col = (t&15)*16, 4 passes (was 8x32-lane rows
//    overrunning the 266-pitch and stomping neighbor tiles).
//  - gemm loop r13, attn r18 dbuf, dw r13 4-row, transpose_v restored.
// ============================================================================

#define HW 65536
#define IMW 256

typedef short bf16x8 __attribute__((ext_vector_type(8)));
typedef float f32x4  __attribute__((ext_vector_type(4)));

__device__ __forceinline__ float bf2f(ushort u) {
    return __uint_as_float((uint)u << 16);
}
__device__ __forceinline__ ushort f2bf(float f) {
    uint i = __float_as_uint(f);
    return (ushort)((i + 0x7FFFu + ((i >> 16) & 1u)) >> 16);
}

__device__ __forceinline__ void gload16(const ushort* g, ushort* l) {
    __builtin_amdgcn_global_load_lds(
        (const __attribute__((address_space(1))) void*)g,
        (__attribute__((address_space(3))) void*)l,
        16, 0, 0);
}

// ---- flat fp32 -> bf16 (weights)
__global__ __launch_bounds__(256) void cvt_f32_bf16(const float* __restrict__ s,
                                                    ushort* __restrict__ d, int n)
{
    int i = blockIdx.x * 256 + threadIdx.x;
    if (i < n) d[i] = f2bf(s[i]);
}

// ---- fp32 [R][C] -> bf16 [C][R] transpose+convert, 64x64 tiles, z-sliced
__global__ __launch_bounds__(256) void cvt_transpose_f32(const float* __restrict__ src,
                                                         ushort* __restrict__ dst,
                                                         int R, int C,
                                                         long ssS, long ssD)
{
    __shared__ ushort Ls[64][72];
    int t = threadIdx.x;
    long z = blockIdx.z;
    src += z * ssS; dst += z * ssD;
    int c0 = blockIdx.x * 64, r0 = blockIdx.y * 64;
    {
        int r = t >> 2, cs = t & 3;
        const float* gp = src + (size_t)(r0 + r) * C + c0 + cs * 16;
        ushort tmp[16];
        #pragma unroll
        for (int q = 0; q < 4; ++q) {
            float4 v = *(const float4*)(gp + q * 4);
            tmp[q*4+0] = f2bf(v.x); tmp[q*4+1] = f2bf(v.y);
            tmp[q*4+2] = f2bf(v.z); tmp[q*4+3] = f2bf(v.w);
        }
        *(uint4*)&Ls[r][cs * 16]     = *(uint4*)&tmp[0];
        *(uint4*)&Ls[r][cs * 16 + 8] = *(uint4*)&tmp[8];
    }
    __syncthreads();
    {
        int cc = t & 63, seg = t >> 6;
        ushort tmp[16];
        #pragma unroll
        for (int j = 0; j < 16; ++j) tmp[j] = Ls[seg * 16 + j][cc];
        ushort* op = dst + (size_t)(c0 + cc) * R + r0 + seg * 16;
        *(uint4*)(op)     = *(uint4*)&tmp[0];
        *(uint4*)(op + 8) = *(uint4*)&tmp[8];
    }
}

// ---- bf16 [R][C] -> bf16 [C][R] transpose, 64x64 tiles, z-sliced
__global__ __launch_bounds__(256) void transpose_bf16(const ushort* __restrict__ src,
                                                      ushort* __restrict__ dst,
                                                      int R, int C,
                                                      long ssS, long ssD)
{
    __shared__ ushort Ls[64][72];
    int t = threadIdx.x;
    long z = blockIdx.z;
    src += z * ssS; dst += z * ssD;
    int c0 = blockIdx.x * 64, r0 = blockIdx.y * 64;
    {
        int r = t >> 2, cs = t & 3;
        const ushort* gp = src + (size_t)(r0 + r) * C + c0 + cs * 16;
        *(uint4*)&Ls[r][cs * 16]     = *(const uint4*)(gp);
        *(uint4*)&Ls[r][cs * 16 + 8] = *(const uint4*)(gp + 8);
    }
    __syncthreads();
    {
        int cc = t & 63, seg = t >> 6;
        ushort tmp[16];
        #pragma unroll
        for (int j = 0; j < 16; ++j) tmp[j] = Ls[seg * 16 + j][cc];
        ushort* op = dst + (size_t)(c0 + cc) * R + r0 + seg * 16;
        *(uint4*)(op)     = *(uint4*)&tmp[0];
        *(uint4*)(op + 8) = *(uint4*)&tmp[8];
    }
}

// ---- V [b][384+r][256][256] -> Vt [s=b*192+r][256][256]^T
__global__ __launch_bounds__(256) void transpose_v(const ushort* __restrict__ post,
                                                   ushort* __restrict__ vt)
{
    __shared__ ushort Ls[64][72];
    int t = threadIdx.x;
    int s = blockIdx.z;
    int b = s / 192, r = s - b * 192;
    const ushort* src = post + ((size_t)b * 576 + 384 + r) * HW;
    ushort*       dst = vt + (size_t)s * HW;
    int c0 = blockIdx.x * 64, r0 = blockIdx.y * 64;
    {
        int rr = t >> 2, cs = t & 3;
        const ushort* gp = src + (size_t)(r0 + rr) * IMW + c0 + cs * 16;
        *(uint4*)&Ls[rr][cs * 16]     = *(const uint4*)(gp);
        *(uint4*)&Ls[rr][cs * 16 + 8] = *(const uint4*)(gp + 8);
    }
    __syncthreads();
    {
        int cc = t & 63, seg = t >> 6;
        ushort tmp[16];
        #pragma unroll
        for (int j = 0; j < 16; ++j) tmp[j] = Ls[seg * 16 + j][cc];
        ushort* op = dst + (size_t)(c0 + cc) * IMW + r0 + seg * 16;
        *(uint4*)(op)     = *(uint4*)&tmp[0];
        *(uint4*)(op + 8) = *(uint4*)&tmp[8];
    }
}

// ---- MFMA GEMM (r13 loop): dbuf LDS, gload_lds, 1 barrier/iter.
// bf16 epilogue restaged through the dead loop-LDS for coalesced 16B stores.
__global__ __launch_bounds__(256) void gemm_mfma(const ushort* __restrict__ A, int lda, long sliceA,
                                                 const ushort* __restrict__ B, int ldb, long sliceB,
                                                 void* __restrict__ Dp, int ldd, long sliceD,
                                                 const float* __restrict__ bias,
                                                 int K, int outF32, int NM, int NN)
{
    int lin = blockIdx.x;
    int r8 = lin & 7, kk_ = lin >> 3;
    int m = kk_ % NM, fg = kk_ / NM;
    int g = fg * 8 + r8;
    int nt_ = g % NN;
    long z = g / NN;
    int m0 = m * 64;
    int n0 = nt_ * 256;

    __shared__ ushort SMEM[20480];    // 40 KB: Ws[2][64][32] | Xs[2][256][32]
    ushort* WsP = SMEM;               // buf*2048 + row*32 + col
    ushort* XsP = SMEM + 4096;        // buf*8192 + row*32 + col
    int t = threadIdx.x, wv = t >> 6, lane = t & 63;
    int fr = lane & 15, sg = lane >> 4;
    A += z * sliceA; B += z * sliceB;

    int rl   = wv * 16 + (lane >> 2);
    int chnk = (lane & 3) ^ ((lane >> 3) & 3);
    const ushort* srcA  = A + (size_t)(m0 + rl) * lda + chnk * 8;
    const ushort* srcB0 = B + (size_t)(n0 +       rl) * ldb + chnk * 8;
    const ushort* srcB1 = B + (size_t)(n0 +  64 + rl) * ldb + chnk * 8;
    const ushort* srcB2 = B + (size_t)(n0 + 128 + rl) * ldb + chnk * 8;
    const ushort* srcB3 = B + (size_t)(n0 + 192 + rl) * ldb + chnk * 8;

    int sp = sg ^ ((fr >> 1) & 3);

    f32x4 acc[4][4];
    #pragma unroll
    for (int i = 0; i < 4; ++i)
        #pragma unroll
        for (int j = 0; j < 4; ++j) acc[i][j] = (f32x4){0.f, 0.f, 0.f, 0.f};

    gload16(srcA,  &WsP[(wv * 16) * 32]);
    gload16(srcB0, &XsP[(      wv * 16) * 32]);
    gload16(srcB1, &XsP[( 64 + wv * 16) * 32]);
    gload16(srcB2, &XsP[(128 + wv * 16) * 32]);
    gload16(srcB3, &XsP[(192 + wv * 16) * 32]);
    __syncthreads();

    int nkit = K >> 5;
    for (int kit = 0; kit < nkit; ++kit) {
        int cur = kit & 1;
        if (kit + 1 < nkit) {
            int kn = (kit + 1) * 32;
            int nb = cur ^ 1;
            gload16(srcA  + kn, &WsP[nb * 2048 + (wv * 16) * 32]);
            gload16(srcB0 + kn, &XsP[nb * 8192 + (      wv * 16) * 32]);
            gload16(srcB1 + kn, &XsP[nb * 8192 + ( 64 + wv * 16) * 32]);
            gload16(srcB2 + kn, &XsP[nb * 8192 + (128 + wv * 16) * 32]);
            gload16(srcB3 + kn, &XsP[nb * 8192 + (192 + wv * 16) * 32]);
        }
        bf16x8 a[4];
        #pragma unroll
        for (int i = 0; i < 4; ++i)
            a[i] = *(const bf16x8*)&WsP[cur * 2048 + (i * 16 + fr) * 32 + sp * 8];
        #pragma unroll
        for (int j = 0; j < 4; ++j) {
            bf16x8 b = *(const bf16x8*)&XsP[cur * 8192 + (wv * 64 + j * 16 + fr) * 32 + sp * 8];
            #pragma unroll
            for (int i = 0; i < 4; ++i)
                acc[i][j] = __builtin_amdgcn_mfma_f32_16x16x32_bf16(a[i], b, acc[i][j], 0, 0, 0);
        }
        __syncthreads();
    }

    int rbase = sg * 4;
    if (outF32) {
        // fp32 path: direct stores (4B x 16 lanes = 64B segments, coalesced)
        float* D = (float*)Dp + z * sliceD;
        int nw0 = n0 + wv * 64;
        #pragma unroll
        for (int i = 0; i < 4; ++i) {
            #pragma unroll
            for (int r_ = 0; r_ < 4; ++r_) {
                int mrow = m0 + i * 16 + rbase + r_;
                float bv = bias ? bias[mrow] : 0.f;
                #pragma unroll
                for (int j = 0; j < 4; ++j)
                    D[(size_t)mrow * ldd + nw0 + j * 16 + fr] = acc[i][j][r_] + bv;
            }
        }
    } else {
        // bf16 path: restage 64x256 tile through LDS (pitch 266), then
        // coalesced stores: 16 lanes x 16 ushorts per row, 4 passes.
        ushort* Es = SMEM;            // [64][266] = 17024 ushorts <= 20480
        #pragma unroll
        for (int i = 0; i < 4; ++i) {
            #pragma unroll
            for (int r_ = 0; r_ < 4; ++r_) {
                int lr = i * 16 + rbase + r_;
                float bv = bias ? bias[m0 + lr] : 0.f;
                #pragma unroll
                for (int j = 0; j < 4; ++j)
                    Es[lr * 266 + wv * 64 + j * 16 + fr] = f2bf(acc[i][j][r_] + bv);
            }
        }
        __syncthreads();
        ushort* D = (ushort*)Dp + z * sliceD;
        int rr = t >> 4;              // 0..15
        int cc = (t & 15) * 16;       // 0..240 (ushort units), 16 per lane
        #pragma unroll
        for (int pass = 0; pass < 4; ++pass) {
            int row = pass * 16 + rr;
            uint4 v = *(const uint4*)&Es[row * 266 + cc];
            uint4 w = *(const uint4*)&Es[row * 266 + cc + 8];
            ushort* op = D + (size_t)(m0 + row) * ldd + n0 + cc;
            *(uint4*)(op)     = v;
            *(uint4*)(op + 8) = w;
        }
    }
}

// ---- fused attention (r18 dbuf): 1 barrier/iter, V0 prefetch under softmax
__global__ __launch_bounds__(256) void attn_fused(const ushort* __restrict__ post,
                                                  const ushort* __restrict__ vt,
                                                  const float* __restrict__ temp,
                                                  ushort* __restrict__ O)
{
    __shared__ ushort Ws[2][64][32];
    __shared__ ushort Xs[2][256][32];
    __shared__ ushort Ps[64][264];
    int t = threadIdx.x, wv = t >> 6, lane = t & 63;
    int fr = lane & 15, sg = lane >> 4;
    int lin = blockIdx.x;
    int r8 = lin & 7, k_ = lin >> 3;
    int mtile = k_ & 3, fg = k_ >> 2;
    int s = fg * 8 + r8;
    int b = s / 192, ch = s - b * 192;
    const ushort* Aq = post + ((size_t)b * 576 + ch) * HW;
    const ushort* Bk = Aq + (size_t)192 * HW;
    const ushort* Vt = vt + (size_t)s * HW;
    int m0 = mtile * 64;

    int rl   = wv * 16 + (lane >> 2);
    int chnk = (lane & 3) ^ ((lane >> 3) & 3);
    int sp   = sg ^ ((fr >> 1) & 3);
    const ushort* srcQ  = Aq + (size_t)(m0 + rl) * IMW + chnk * 8;
    const ushort* srcK0 = Bk + (size_t)(      rl) * IMW + chnk * 8;
    const ushort* srcK1 = Bk + (size_t)( 64 + rl) * IMW + chnk * 8;
    const ushort* srcK2 = Bk + (size_t)(128 + rl) * IMW + chnk * 8;
    const ushort* srcK3 = Bk + (size_t)(192 + rl) * IMW + chnk * 8;
    const ushort* srcV0 = Vt + (size_t)(      rl) * IMW + chnk * 8;
    const ushort* srcV1 = Vt + (size_t)( 64 + rl) * IMW + chnk * 8;
    const ushort* srcV2 = Vt + (size_t)(128 + rl) * IMW + chnk * 8;
    const ushort* srcV3 = Vt + (size_t)(192 + rl) * IMW + chnk * 8;

    f32x4 acc[16];
    #pragma unroll
    for (int i = 0; i < 16; ++i) acc[i] = (f32x4){0.f, 0.f, 0.f, 0.f};

    gload16(srcQ,  &Ws[0][wv * 16][0]);
    gload16(srcK0, &Xs[0][      wv * 16][0]);
    gload16(srcK1, &Xs[0][ 64 + wv * 16][0]);
    gload16(srcK2, &Xs[0][128 + wv * 16][0]);
    gload16(srcK3, &Xs[0][192 + wv * 16][0]);
    __syncthreads();

    for (int kit = 0; kit < 8; ++kit) {
        int cur = kit & 1;
        if (kit < 7) {
            int kn = (kit + 1) * 32;
            gload16(srcQ  + kn, &Ws[cur ^ 1][wv * 16][0]);
            gload16(srcK0 + kn, &Xs[cur ^ 1][      wv * 16][0]);
            gload16(srcK1 + kn, &Xs[cur ^ 1][ 64 + wv * 16][0]);
            gload16(srcK2 + kn, &Xs[cur ^ 1][128 + wv * 16][0]);
            gload16(srcK3 + kn, &Xs[cur ^ 1][192 + wv * 16][0]);
        }
        bf16x8 a = *(const bf16x8*)&Ws[cur][wv * 16 + fr][sp * 8];
        #pragma unroll
        for (int nt = 0; nt < 16; ++nt) {
            bf16x8 bfrag = *(const bf16x8*)&Xs[cur][nt * 16 + fr][sp * 8];
            acc[nt] = __builtin_amdgcn_mfma_f32_16x16x32_bf16(a, bfrag, acc[nt], 0, 0, 0);
        }
        __syncthreads();
    }

    gload16(srcV0, &Xs[0][      wv * 16][0]);
    gload16(srcV1, &Xs[0][ 64 + wv * 16][0]);
    gload16(srcV2, &Xs[0][128 + wv * 16][0]);
    gload16(srcV3, &Xs[0][192 + wv * 16][0]);

    float tv = temp[ch >> 5];
    #pragma unroll
    for (int r_ = 0; r_ < 4; ++r_) {
        float v[16];
        float mx = -3.4e38f;
        #pragma unroll
        for (int nt = 0; nt < 16; ++nt) { v[nt] = acc[nt][r_] * tv; mx = fmaxf(mx, v[nt]); }
        #pragma unroll
        for (int sh = 1; sh < 16; sh <<= 1) mx = fmaxf(mx, __shfl_xor(mx, sh, 64));
        float sum = 0.f;
        #pragma unroll
        for (int nt = 0; nt < 16; ++nt) { v[nt] = __expf(v[nt] - mx); sum += v[nt]; }
        #pragma unroll
        for (int sh = 1; sh < 16; sh <<= 1) sum += __shfl_xor(sum, sh, 64);
        float inv = 1.f / sum;
        int ml = wv * 16 + sg * 4 + r_;
        #pragma unroll
        for (int nt = 0; nt < 16; ++nt)
            Ps[ml][fr + nt * 16] = f2bf(v[nt] * inv);
    }
    __syncthreads();

    f32x4 acc2[16];
    #pragma unroll
    for (int i = 0; i < 16; ++i) acc2[i] = (f32x4){0.f, 0.f, 0.f, 0.f};

    for (int y = 0; y < 8; ++y) {
        int cur = y & 1;
        if (y < 7) {
            int yn = (y + 1) * 32;
            gload16(srcV0 + yn, &Xs[cur ^ 1][      wv * 16][0]);
            gload16(srcV1 + yn, &Xs[cur ^ 1][ 64 + wv * 16][0]);
            gload16(srcV2 + yn, &Xs[cur ^ 1][128 + wv * 16][0]);
            gload16(srcV3 + yn, &Xs[cur ^ 1][192 + wv * 16][0]);
        }
        bf16x8 a = *(const bf16x8*)&Ps[wv * 16 + fr][y * 32 + sg * 8];
        #pragma unroll
        for (int nt = 0; nt < 16; ++nt) {
            bf16x8 bfrag = *(const bf16x8*)&Xs[cur][nt * 16 + fr][sp * 8];
            acc2[nt] = __builtin_amdgcn_mfma_f32_16x16x32_bf16(a, bfrag, acc2[nt], 0, 0, 0);
        }
        __syncthreads();
    }

    ushort* Op = O + (size_t)s * HW;
    int mrow = m0 + wv * 16 + sg * 4;
    #pragma unroll
    for (int r_ = 0; r_ < 4; ++r_) {
        #pragma unroll
        for (int nt = 0; nt < 16; ++nt)
            Op[(size_t)(mrow + r_) * IMW + fr + nt * 16] = f2bf(acc2[nt][r_]);
    }
}

// ---- depthwise 3x3 SAME + fused L2 row-norm (r13 exact: 4 rows/wave)
__global__ __launch_bounds__(256) void dw3x3_l2norm(const ushort* __restrict__ in,
                                                    const float* __restrict__ w,
                                                    const float* __restrict__ bias,
                                                    ushort* __restrict__ out)
{
    int t = threadIdx.x;
    int lane = t & 63, wv = t >> 6;
    int ch = blockIdx.y;
    int r0 = blockIdx.x * 16 + wv * 4;
    const ushort* img  = in  + ((size_t)blockIdx.z * 576 + ch) * HW;
    ushort*       outp = out + ((size_t)blockIdx.z * 576 + ch) * HW;
    int px = lane * 4;

    float rv[6][4], lv[6], rx[6];
    #pragma unroll
    for (int i = 0; i < 6; ++i) {
        int rr = r0 - 1 + i;
        if ((unsigned)rr <= 255u) {
            ushort4 cv = *(const ushort4*)&img[(size_t)rr * IMW + px];
            rv[i][0] = bf2f(cv.x); rv[i][1] = bf2f(cv.y);
            rv[i][2] = bf2f(cv.z); rv[i][3] = bf2f(cv.w);
        } else {
            rv[i][0] = rv[i][1] = rv[i][2] = rv[i][3] = 0.f;
        }
        float l = __shfl_up(rv[i][3], 1, 64);
        lv[i] = (lane == 0) ? 0.f : l;
        float r = __shfl_down(rv[i][0], 1, 64);
        rx[i] = (lane == 63) ? 0.f : r;
    }

    const float* wch = w + ch * 9;
    float bv = bias[ch];
    bool do_norm = (ch < 384);

    #pragma unroll
    for (int j = 0; j < 4; ++j) {
        float a0 = bv, a1 = bv, a2 = bv, a3 = bv;
        #pragma unroll
        for (int dy = 0; dy < 3; ++dy) {
            int i = j + dy;
            float w0 = wch[dy * 3], w1 = wch[dy * 3 + 1], w2 = wch[dy * 3 + 2];
            a0 += lv[i]    * w0 + rv[i][0] * w1 + rv[i][1] * w2;
            a1 += rv[i][0] * w0 + rv[i][1] * w1 + rv[i][2] * w2;
            a2 += rv[i][1] * w0 + rv[i][2] * w1 + rv[i][3] * w2;
            a3 += rv[i][2] * w0 + rv[i][3] * w1 + rx[i]    * w2;
        }
        if (do_norm) {
            float ss = a0 * a0 + a1 * a1 + a2 * a2 + a3 * a3;
            #pragma unroll
            for (int m = 1; m < 64; m <<= 1) ss += __shfl_xor(ss, m, 64);
            float inv = 1.0f / fmaxf(sqrtf(ss), 1e-12f);
            a0 *= inv; a1 *= inv; a2 *= inv; a3 *= inv;
        }
        ushort4 o;
        o.x = f2bf(a0); o.y = f2bf(a1); o.z = f2bf(a2); o.w = f2bf(a3);
        *(ushort4*)&outp[(size_t)(r0 + j) * IMW + px] = o;
    }
}

extern "C" void kernel_launch(void* const* d_in, const int* in_sizes, int n_in,
                              void* d_out, int out_size, void* d_ws, size_t ws_size,
                              hipStream_t stream)
{
    const float* x      = (const float*)d_in[0];
    const float* qkv_w  = (const float*)d_in[1];
    const float* qkv_b  = (const float*)d_in[2];
    const float* dw_w   = (const float*)d_in[3];
    const float* dw_b   = (const float*)d_in[4];
    const float* proj_w = (const float*)d_in[5];
    const float* proj_b = (const float*)d_in[6];
    const float* temp   = (const float*)d_in[7];
    float* out = (float*)d_out;

    const size_t off_wq   = 0;
    const size_t off_wp   = 110592;
    const size_t off_pre  = 262144;
    const size_t off_post = off_pre + (size_t)4 * 576 * HW;
    const size_t off_xt   = off_post + (size_t)4 * 576 * HW;
    const size_t total_us = off_xt + (size_t)4 * 192 * HW;
    if (ws_size < total_us * sizeof(ushort)) return;

    ushort* wsb  = (ushort*)d_ws;
    ushort* wq   = wsb + off_wq;
    ushort* wp   = wsb + off_wp;
    ushort* pre  = wsb + off_pre;
    ushort* post = wsb + off_post;
    ushort* xt   = wsb + off_xt;
    ushort* Obuf = pre;
    ushort* Otb  = pre + (size_t)4 * 192 * HW;

    const long SL = (long)192 * HW;

    cvt_f32_bf16<<<dim3(432), 256, 0, stream>>>(qkv_w, wq, 110592);
    cvt_f32_bf16<<<dim3(144), 256, 0, stream>>>(proj_w, wp, 36864);

    cvt_transpose_f32<<<dim3(1024, 3, 4), 256, 0, stream>>>(x, xt, 192, HW, SL, SL);
    // qkv: NM=9, NN=256, 4 batches -> 9216 blocks
    gemm_mfma<<<dim3(9 * 256 * 4), 256, 0, stream>>>(wq, 192, 0, xt, 192, SL,
                                                     pre, HW, (long)576 * HW,
                                                     qkv_b, 192, 0, 9, 256);
    dw3x3_l2norm<<<dim3(16, 576, 4), 256, 0, stream>>>(pre, dw_w, dw_b, post);
    transpose_v<<<dim3(4, 4, 768), 256, 0, stream>>>(post, xt);
    attn_fused<<<dim3(4 * 768), 256, 0, stream>>>(post, xt, temp, Obuf);
    transpose_bf16<<<dim3(1024, 3, 4), 256, 0, stream>>>(Obuf, Otb, 192, HW, SL, SL);
    // proj: NM=3, NN=256, 4 batches -> 3072 blocks
    gemm_mfma<<<dim3(3 * 256 * 4), 256, 0, stream>>>(wp, 192, 0, Otb, 192, SL,
                                                     out, HW, SL,
                                                     proj_b, 192, 1, 3, 256);
}